// Round 1
// baseline (2141.402 us; speedup 1.0000x reference)
//
#include <hip/hip_runtime.h>
#include <hip/hip_bf16.h>
#include <stdint.h>

#define DEV __device__ __forceinline__

typedef unsigned short u16;
typedef __attribute__((ext_vector_type(8))) short bf16x8;
typedef __attribute__((ext_vector_type(4))) float f32x4;

constexpr int H  = 256;
constexpr int R  = 480;
constexpr int NE = 23000;
constexpr int NT = 8192;
constexpr int TT = 10;

DEV u16 f2b(float f) {
  union { float f; unsigned u; } x; x.f = f;
  unsigned u = x.u;
  return (u16)((u + 0x7fffu + ((u >> 16) & 1u)) >> 16);
}
DEV float b2f(u16 h) {
  union { unsigned u; float f; } x; x.u = ((unsigned)h) << 16;
  return x.f;
}

DEV void gload_lds16(const u16* g, u16* lds) {
  __builtin_amdgcn_global_load_lds(
      (const __attribute__((address_space(1))) unsigned int*)g,
      (__attribute__((address_space(3))) unsigned int*)lds, 16, 0, 0);
}

// ---------------- init: zero h (f32) and h_b (bf16) ----------------
__global__ void init_k(float* __restrict__ h, unsigned int* __restrict__ hb) {
  const int idx = blockIdx.x * 256 + threadIdx.x;   // 8192*256 threads
  h[idx] = 0.f;
  if (idx < (NT * H) / 2) hb[idx] = 0u;
}

// ---------------- generic small f32 GEMM: C = scale*(A@W + bias) + add ----
__global__ void sgemm_k(const float* __restrict__ A, const float* __restrict__ W,
                        const float* __restrict__ bias, const float* __restrict__ add,
                        float scale, float* __restrict__ C,
                        int M, int N, int K, int transW) {
  const int idx = blockIdx.x * 256 + threadIdx.x;
  if (idx >= M * N) return;
  const int i = idx / N, j = idx % N;
  float s = bias ? bias[j] : 0.f;
  const float* a = A + (size_t)i * K;
  if (!transW) {
    for (int k = 0; k < K; ++k) s += a[k] * W[(size_t)k * N + j];
  } else {
    const float* w = W + (size_t)j * K;
    for (int k = 0; k < K; ++k) s += a[k] * w[k];
  }
  C[idx] = scale * s + (add ? add[idx] : 0.f);
}

// ---------------- transpose f32 -> bf16: W[K][Nn] -> Wt[Nn][K] -------------
__global__ void transpose_w_k(const float* __restrict__ W, u16* __restrict__ Wt,
                              int K, int Nn) {
  const int idx = blockIdx.x * 256 + threadIdx.x;
  if (idx >= K * Nn) return;
  const int k = idx / Nn, n = idx % Nn;
  Wt[(size_t)n * K + k] = f2b(W[idx]);
}

// ---------------- G2 = GRUcell(x=mapped, h=P) per rel row ------------------
__global__ void g2_k(const float* __restrict__ MW, const float* __restrict__ PW,
                     const float* __restrict__ P, const float* __restrict__ bih,
                     float* __restrict__ G2) {
  const int idx = blockIdx.x * 256 + threadIdx.x;   // 480*256
  if (idx >= R * H) return;
  const int r = idx >> 8, c = idx & 255;
  const float* mw = MW + (size_t)r * 768;
  const float* pw = PW + (size_t)r * 768;
  const float ir = mw[c] + bih[c];
  const float iz = mw[c + 256] + bih[c + 256];
  const float in_ = mw[c + 512] + bih[c + 512];
  const float rr = 1.f / (1.f + __expf(-(ir + pw[c])));
  const float z  = 1.f / (1.f + __expf(-(iz + pw[c + 256])));
  const float n  = tanhf(in_ + rr * pw[c + 512]);
  G2[idx] = (1.f - z) * n + z * P[idx];
}

// ---------------- per-row masked softmax over 480 rels ---------------------
__global__ void softmax_k(const float* __restrict__ part, const float* __restrict__ B480,
                          const int* __restrict__ rel_idx, u16* __restrict__ attn, int t) {
  const int i = blockIdx.x;          // 8192 rows
  const int lane = threadIdx.x;      // 64 threads
  const float* cur = part + (size_t)i * (TT * R) + (size_t)t * R;
  const float* b = B480 + (size_t)rel_idx[i] * R;
  float v[8];
  float m = -3e38f;
  #pragma unroll
  for (int j = 0; j < 8; ++j) {
    const int r = lane + j * 64;
    float val = -1e9f;
    if (r < R) {
      const float c = cur[r];
      val = (c == 0.f) ? -1e9f : c * b[r];
      m = fmaxf(m, val);
    }
    v[j] = val;
  }
  #pragma unroll
  for (int o = 32; o; o >>= 1) m = fmaxf(m, __shfl_xor(m, o));
  float s = 0.f;
  #pragma unroll
  for (int j = 0; j < 8; ++j) {
    const int r = lane + j * 64;
    if (r < R) { v[j] = __expf(v[j] - m); s += v[j]; }
  }
  #pragma unroll
  for (int o = 32; o; o >>= 1) s += __shfl_xor(s, o);
  const float inv = 1.f / s;
  u16* arow = attn + (size_t)i * R;
  #pragma unroll
  for (int j = 0; j < 8; ++j) {
    const int r = lane + j * 64;
    if (r < R) arow[r] = f2b(v[j] * inv);
  }
}

// ---------------- GRU gates for the scan (in-place h update) ---------------
__global__ void gates_k(const float* __restrict__ gi, const float* __restrict__ gh,
                        float* __restrict__ h, u16* __restrict__ hb) {
  const int idx = blockIdx.x * 256 + threadIdx.x;   // 8192*256
  const int i = idx >> 8, c = idx & 255;
  const float* giR = gi + (size_t)i * 768;
  const float* ghR = gh + (size_t)i * 768;
  const float r = 1.f / (1.f + __expf(-(giR[c] + ghR[c])));
  const float z = 1.f / (1.f + __expf(-(giR[c + 256] + ghR[c + 256])));
  const float n = tanhf(giR[c + 512] + r * ghR[c + 512]);
  const float ho = (1.f - z) * n + z * h[idx];
  h[idx] = ho;
  hb[idx] = f2b(ho);
}

// ---------------- gathers / converts ---------------------------------------
__global__ void gather_sub_k(const float* __restrict__ pre, const int* __restrict__ sub,
                             u16* __restrict__ sb) {
  const int idx = blockIdx.x * 256 + threadIdx.x;   // 8192*256
  const int i = idx >> 8, c = idx & 255;
  sb[idx] = f2b(pre[(size_t)sub[i] * H + c]);
}
__global__ void cvt_pre_k(const float* __restrict__ pre, u16* __restrict__ pb) {
  const int idx = blockIdx.x * 256 + threadIdx.x;   // 23000*256
  pb[idx] = f2b(pre[idx]);
}

// ---------------- lhs = asub * G2[rel]; match partial sums -----------------
__global__ void lhsmatch_k(const int* __restrict__ rel_idx, const float* __restrict__ P,
                           const float* __restrict__ G2, const float* __restrict__ h,
                           const float* __restrict__ asub, u16* __restrict__ lhs,
                           float* __restrict__ mpart) {
  const int tid = threadIdx.x;
  const int blk = blockIdx.x;        // 2048 blocks, 1024 elems each
  float local = 0.f;
  #pragma unroll
  for (int u = 0; u < 4; ++u) {
    const int idx = blk * 1024 + u * 256 + tid;
    const int i = idx >> 8, c = idx & 255;
    const int rel = rel_idx[i];
    const float d = P[(size_t)rel * H + c] - h[idx];
    local += d * d;
    lhs[idx] = f2b(asub[idx] * G2[(size_t)rel * H + c]);
  }
  #pragma unroll
  for (int o = 32; o; o >>= 1) local += __shfl_down(local, o);
  __shared__ float red[4];
  if ((tid & 63) == 0) red[tid >> 6] = local;
  __syncthreads();
  if (tid == 0) mpart[blk] = red[0] + red[1] + red[2] + red[3];
}

// ---------------- pos_i = dot(lhs[i], alignedT[obj[i]]) --------------------
__global__ void pos_k(const u16* __restrict__ lhs, const u16* __restrict__ alT,
                      const int* __restrict__ obj, float* __restrict__ pos) {
  const int row = blockIdx.x * 4 + (threadIdx.x >> 6);
  const int lane = threadIdx.x & 63;
  const u16* a = lhs + (size_t)row * H;
  const u16* b = alT + (size_t)obj[row] * H;
  float s = 0.f;
  #pragma unroll
  for (int j = 0; j < 4; ++j) {
    const int c = lane + j * 64;
    s += b2f(a[c]) * b2f(b[c]);
  }
  #pragma unroll
  for (int o = 32; o; o >>= 1) s += __shfl_down(s, o);
  if (lane == 0) pos[row] = s;
}

// ---------------- final scalar reduction -----------------------------------
__global__ void finalize_k(const float* __restrict__ mp, const float* __restrict__ sp,
                           const float* __restrict__ pos, float* __restrict__ out) {
  const int tid = threadIdx.x;
  float s1 = 0.f, s2 = 0.f, s3 = 0.f;
  for (int i = tid; i < 2048; i += 256) s1 += mp[i];
  for (int i = tid; i < 11520; i += 256) s2 += sp[i];
  for (int i = tid; i < 8192; i += 256) s3 += pos[i];
  #pragma unroll
  for (int o = 32; o; o >>= 1) {
    s1 += __shfl_down(s1, o); s2 += __shfl_down(s2, o); s3 += __shfl_down(s3, o);
  }
  __shared__ float r1[4], r2[4], r3[4];
  if ((tid & 63) == 0) { r1[tid >> 6] = s1; r2[tid >> 6] = s2; r3[tid >> 6] = s3; }
  __syncthreads();
  if (tid == 0) {
    const float a = r1[0] + r1[1] + r1[2] + r1[3];
    const float b = r2[0] + r2[1] + r2[2] + r2[3];
    const float c = r3[0] + r3[1] + r3[2] + r3[3];
    out[0] = a / 2097152.f;               // mean over 8192*256
    out[1] = (b - c) / 188416000.f;       // (softplus sum - pos sum)/(8192*23000)
  }
}

// ---------------- bf16 MFMA GEMM: C[M,N] = A[M,K] @ Bt[N,K]^T --------------
// MODE 0: C = A@B + bias -> Cf (f32) and/or Cb (bf16)
// MODE 1: score epilogue: sigmoid -> out2, softplus partial -> part[]
template <int MODE>
__launch_bounds__(256)
__global__ void gemm_k(const u16* __restrict__ A, const u16* __restrict__ Bt,
                       const float* __restrict__ bias,
                       float* __restrict__ Cf, u16* __restrict__ Cb,
                       int M, int N, int K,
                       float* __restrict__ out2, float* __restrict__ part) {
  __shared__ __align__(16) u16 As[128 * 32];
  __shared__ __align__(16) u16 Bs[128 * 32];
  __shared__ float red[4];
  const int tid = threadIdx.x;
  const int lane = tid & 63;
  const int wv = tid >> 6;
  const int m0 = blockIdx.y * 128;
  const int n0 = blockIdx.x * 128;
  const int wm = (wv >> 1) * 64;
  const int wn = (wv & 1) * 64;
  const int fr = lane & 15;
  const int fq = lane >> 4;
  f32x4 acc[4][4] = {};

  for (int k0 = 0; k0 < K; k0 += 32) {
    __syncthreads();
    #pragma unroll
    for (int it = 0; it < 2; ++it) {
      const int c = it * 256 + tid;       // 16B chunk id, 512 per tile
      const int row = c >> 2;
      const int cc = c & 3;
      int gr = m0 + row; gr = gr < M ? gr : M - 1;
      gload_lds16(A + (size_t)gr * K + k0 + cc * 8, &As[(it * 256 + wv * 64) * 8]);
      int nr = n0 + row; nr = nr < N ? nr : N - 1;
      gload_lds16(Bt + (size_t)nr * K + k0 + cc * 8, &Bs[(it * 256 + wv * 64) * 8]);
    }
    __syncthreads();
    bf16x8 a[4], b[4];
    #pragma unroll
    for (int mi = 0; mi < 4; ++mi)
      a[mi] = *(const bf16x8*)&As[(wm + mi * 16 + fr) * 32 + fq * 8];
    #pragma unroll
    for (int ni = 0; ni < 4; ++ni)
      b[ni] = *(const bf16x8*)&Bs[(wn + ni * 16 + fr) * 32 + fq * 8];
    #pragma unroll
    for (int mi = 0; mi < 4; ++mi)
      #pragma unroll
      for (int ni = 0; ni < 4; ++ni)
        acc[mi][ni] = __builtin_amdgcn_mfma_f32_16x16x32_bf16(a[mi], b[ni], acc[mi][ni], 0, 0, 0);
  }

  float local = 0.f;
  #pragma unroll
  for (int mi = 0; mi < 4; ++mi) {
    #pragma unroll
    for (int ni = 0; ni < 4; ++ni) {
      const int col = n0 + wn + ni * 16 + fr;
      float bv = 0.f;
      if (MODE == 0 && bias != nullptr && col < N) bv = bias[col];
      const f32x4 v = acc[mi][ni];
      #pragma unroll
      for (int j = 0; j < 4; ++j) {
        const int rowm = m0 + wm + mi * 16 + fq * 4 + j;
        if (rowm < M && col < N) {
          if (MODE == 0) {
            const float val = v[j] + bv;
            if (Cf) Cf[(size_t)rowm * N + col] = val;
            if (Cb) Cb[(size_t)rowm * N + col] = f2b(val);
          } else {
            const float s = v[j];
            const float sig = 1.f / (1.f + __expf(-s));
            out2[(size_t)rowm * N + col] = sig;
            const float om = 1.f - sig;
            local += (om > 0.f) ? -__logf(om) : s;
          }
        }
      }
    }
  }
  if (MODE == 1) {
    #pragma unroll
    for (int o = 32; o; o >>= 1) local += __shfl_down(local, o);
    if (lane == 0) red[wv] = local;
    __syncthreads();
    if (tid == 0) part[blockIdx.y * gridDim.x + blockIdx.x] = red[0] + red[1] + red[2] + red[3];
  }
}

extern "C" void kernel_launch(void* const* d_in, const int* in_sizes, int n_in,
                              void* d_out, int out_size, void* d_ws, size_t ws_size,
                              hipStream_t stream) {
  const float* pre_emb = (const float*)d_in[0];
  const float* r_emb   = (const float*)d_in[1];
  const float* part_e  = (const float*)d_in[2];
  const int*   sub_idx = (const int*)d_in[3];
  const int*   rel_idx = (const int*)d_in[4];
  const int*   obj_idx = (const int*)d_in[5];
  const float* Wm1 = (const float*)d_in[7];  const float* bm1 = (const float*)d_in[8];
  const float* Wm2 = (const float*)d_in[9];  const float* bm2 = (const float*)d_in[10];
  const float* Wattn = (const float*)d_in[11]; const float* battn = (const float*)d_in[12];
  const float* Wh1 = (const float*)d_in[13]; const float* bh1 = (const float*)d_in[14];
  const float* Wh2 = (const float*)d_in[15]; const float* bh2 = (const float*)d_in[16];
  const float* Walign = (const float*)d_in[17]; const float* balign = (const float*)d_in[18];
  const float* Wih = (const float*)d_in[19]; const float* Whh = (const float*)d_in[20];
  const float* bih = (const float*)d_in[21]; const float* bhh = (const float*)d_in[22];
  float* out = (float*)d_out;

  char* w = (char*)d_ws;
  size_t off = 0;
  auto alloc = [&](size_t bytes) -> void* {
    off = (off + 255) & ~(size_t)255;
    void* p = w + off;
    off += bytes;
    return p;
  };
  float* hidden = (float*)alloc((size_t)R * 512 * 4);
  float* mapped = (float*)alloc((size_t)R * H * 4);
  float* t1     = (float*)alloc((size_t)R * H * 4);
  float* B480   = (float*)alloc((size_t)R * R * 4);
  float* MW     = (float*)alloc((size_t)R * 768 * 4);
  float* p1     = (float*)alloc((size_t)R * H * 4);
  float* P      = (float*)alloc((size_t)R * H * 4);
  float* PW     = (float*)alloc((size_t)R * 768 * 4);
  float* G2     = (float*)alloc((size_t)R * H * 4);
  u16* MWT      = (u16*)alloc((size_t)768 * R * 2);
  u16* WhhT     = (u16*)alloc((size_t)768 * H * 2);
  u16* WalignT  = (u16*)alloc((size_t)H * H * 2);
  u16* attn_b   = (u16*)alloc((size_t)NT * R * 2);
  float* hbuf   = (float*)alloc((size_t)NT * H * 4);
  u16* h_b      = (u16*)alloc((size_t)NT * H * 2);
  float* gi     = (float*)alloc((size_t)NT * 768 * 4);
  float* gh     = (float*)alloc((size_t)NT * 768 * 4);
  float* asub   = (float*)alloc((size_t)NT * H * 4);
  u16* lhs_b    = (u16*)alloc((size_t)NT * H * 2);
  float* mpart  = (float*)alloc(2048 * 4);
  float* spart  = (float*)alloc(11520 * 4);
  float* posar  = (float*)alloc(8192 * 4);
  if (off > ws_size) return;  // workspace insufficient; fail visibly
  u16* sub_b    = (u16*)attn_b;   // alias (attn dead after scan)
  u16* pre_b    = (u16*)gi;       // alias (gi dead after scan epilogue)
  u16* alT      = (u16*)gh;       // alias (gh dead after scan epilogue)

  auto cdiv = [](int a, int b) { return (a + b - 1) / b; };

  // init h = 0
  init_k<<<NT, 256, 0, stream>>>(hbuf, (unsigned int*)h_b);

  // rank-480 precompute (exact f32)
  sgemm_k<<<cdiv(R * 512, 256), 256, 0, stream>>>(r_emb, Wm1, bm1, nullptr, 1.f, hidden, R, 512, H, 0);
  sgemm_k<<<cdiv(R * H, 256), 256, 0, stream>>>(hidden, Wm2, bm2, nullptr, 1.f, mapped, R, H, 512, 0);
  sgemm_k<<<cdiv(R * H, 256), 256, 0, stream>>>(mapped, Wattn, battn, nullptr, 1.f, t1, R, H, H, 0);
  sgemm_k<<<cdiv(R * R, 256), 256, 0, stream>>>(t1, mapped, nullptr, nullptr, 1.f, B480, R, R, H, 1);
  sgemm_k<<<cdiv(R * 768, 256), 256, 0, stream>>>(mapped, Wih, nullptr, nullptr, 1.f, MW, R, 768, H, 0);
  sgemm_k<<<cdiv(R * H, 256), 256, 0, stream>>>(mapped, Wh1, bh1, nullptr, 1.f, p1, R, H, H, 0);
  sgemm_k<<<cdiv(R * H, 256), 256, 0, stream>>>(p1, Wh2, bh2, mapped, 0.1f, P, R, H, H, 0);
  sgemm_k<<<cdiv(R * 768, 256), 256, 0, stream>>>(P, Whh, bhh, nullptr, 1.f, PW, R, 768, H, 0);
  g2_k<<<cdiv(R * H, 256), 256, 0, stream>>>(MW, PW, P, bih, G2);
  transpose_w_k<<<cdiv(R * 768, 256), 256, 0, stream>>>(MW, MWT, R, 768);
  transpose_w_k<<<cdiv(H * 768, 256), 256, 0, stream>>>(Whh, WhhT, H, 768);
  transpose_w_k<<<cdiv(H * H, 256), 256, 0, stream>>>(Walign, WalignT, H, H);

  // scan: 10 steps
  for (int t = 0; t < TT; ++t) {
    softmax_k<<<NT, 64, 0, stream>>>(part_e, B480, rel_idx, attn_b, t);
    gemm_k<0><<<dim3(6, 64), 256, 0, stream>>>(attn_b, MWT, bih, gi, nullptr, NT, 768, R, nullptr, nullptr);
    gemm_k<0><<<dim3(6, 64), 256, 0, stream>>>(h_b, WhhT, bhh, gh, nullptr, NT, 768, H, nullptr, nullptr);
    gates_k<<<NT, 256, 0, stream>>>(gi, gh, hbuf, h_b);
  }

  // aligned sub + lhs + match partials
  gather_sub_k<<<NT, 256, 0, stream>>>(pre_emb, sub_idx, sub_b);
  gemm_k<0><<<dim3(2, 64), 256, 0, stream>>>(sub_b, WalignT, balign, asub, nullptr, NT, H, H, nullptr, nullptr);
  lhsmatch_k<<<2048, 256, 0, stream>>>(rel_idx, P, G2, hbuf, asub, lhs_b, mpart);

  // aligned entity table (bf16, [NE][H] = Bt layout for final GEMM)
  cvt_pre_k<<<NE, 256, 0, stream>>>(pre_emb, pre_b);
  gemm_k<0><<<dim3(2, 180), 256, 0, stream>>>(pre_b, WalignT, balign, nullptr, alT, NE, H, H, nullptr, nullptr);

  // final score GEMM with sigmoid + softplus epilogue
  gemm_k<1><<<dim3(180, 64), 256, 0, stream>>>(lhs_b, alT, nullptr, nullptr, nullptr, NT, NE, H, out + 2, spart);

  // pos + final scalars
  pos_k<<<2048, 256, 0, stream>>>(lhs_b, alT, obj_idx, posar);
  finalize_k<<<1, 256, 0, stream>>>(mpart, spart, posar, out);
}

// Round 2
// 1923.009 us; speedup vs baseline: 1.1136x; 1.1136x over previous
//
#include <hip/hip_runtime.h>
#include <hip/hip_bf16.h>
#include <stdint.h>

#define DEV __device__ __forceinline__

typedef unsigned short u16;
typedef __attribute__((ext_vector_type(8))) short bf16x8;
typedef __attribute__((ext_vector_type(4))) float f32x4;

constexpr int H  = 256;
constexpr int R  = 480;
constexpr int NE = 23000;
constexpr int NT = 8192;
constexpr int TT = 10;

DEV u16 f2b(float f) {
  union { float f; unsigned u; } x; x.f = f;
  unsigned u = x.u;
  return (u16)((u + 0x7fffu + ((u >> 16) & 1u)) >> 16);
}
DEV float b2f(u16 h) {
  union { unsigned u; float f; } x; x.u = ((unsigned)h) << 16;
  return x.f;
}

DEV void gload_lds16(const u16* g, u16* lds) {
  __builtin_amdgcn_global_load_lds(
      (const __attribute__((address_space(1))) unsigned int*)g,
      (__attribute__((address_space(3))) unsigned int*)lds, 16, 0, 0);
}

// ---------------- init: zero h (f32) and h_b0 (bf16) ----------------
__global__ void init_k(float* __restrict__ h, unsigned int* __restrict__ hb) {
  const int idx = blockIdx.x * 256 + threadIdx.x;   // NT*H threads
  h[idx] = 0.f;
  if (idx < (NT * H) / 2) hb[idx] = 0u;
}

// ---------------- generic small f32 GEMM: C = scale*(A@W + bias) + add ----
__global__ void sgemm_k(const float* __restrict__ A, const float* __restrict__ W,
                        const float* __restrict__ bias, const float* __restrict__ add,
                        float scale, float* __restrict__ C,
                        int M, int N, int K, int transW) {
  const int idx = blockIdx.x * 256 + threadIdx.x;
  if (idx >= M * N) return;
  const int i = idx / N, j = idx % N;
  float s = bias ? bias[j] : 0.f;
  const float* a = A + (size_t)i * K;
  if (!transW) {
    for (int k = 0; k < K; ++k) s += a[k] * W[(size_t)k * N + j];
  } else {
    const float* w = W + (size_t)j * K;
    for (int k = 0; k < K; ++k) s += a[k] * w[k];
  }
  C[idx] = scale * s + (add ? add[idx] : 0.f);
}

// ---------------- transpose f32 -> bf16: W[K][Nn] -> Wt[Nn][K] -------------
__global__ void transpose_w_k(const float* __restrict__ W, u16* __restrict__ Wt,
                              int K, int Nn) {
  const int idx = blockIdx.x * 256 + threadIdx.x;
  if (idx >= K * Nn) return;
  const int k = idx / Nn, n = idx % Nn;
  Wt[(size_t)n * K + k] = f2b(W[idx]);
}

// ---------------- combined bias: bih + bhh for r,z chunks; bih for n -------
__global__ void bsum_k(const float* __restrict__ bih, const float* __restrict__ bhh,
                       float* __restrict__ bs) {
  const int c = blockIdx.x * 256 + threadIdx.x;   // 768
  if (c < 768) bs[c] = bih[c] + (c < 512 ? bhh[c] : 0.f);
}

// ---------------- G2 = GRUcell(x=mapped, h=P) per rel row ------------------
__global__ void g2_k(const float* __restrict__ MW, const float* __restrict__ PW,
                     const float* __restrict__ P, const float* __restrict__ bih,
                     float* __restrict__ G2) {
  const int idx = blockIdx.x * 256 + threadIdx.x;   // 480*256
  if (idx >= R * H) return;
  const int r = idx >> 8, c = idx & 255;
  const float* mw = MW + (size_t)r * 768;
  const float* pw = PW + (size_t)r * 768;
  const float ir = mw[c] + bih[c];
  const float iz = mw[c + 256] + bih[c + 256];
  const float in_ = mw[c + 512] + bih[c + 512];
  const float rr = 1.f / (1.f + __expf(-(ir + pw[c])));
  const float z  = 1.f / (1.f + __expf(-(iz + pw[c + 256])));
  const float n  = tanhf(in_ + rr * pw[c + 512]);
  G2[idx] = (1.f - z) * n + z * P[idx];
}

// ---------------- masked softmax for a chunk of steps ----------------------
// task = tt*NT + i  (tt within chunk); writes attn[task][480]
__global__ void softmax_all_k(const float* __restrict__ part, const float* __restrict__ B480,
                              const int* __restrict__ rel_idx, u16* __restrict__ attn,
                              int t0) {
  const int task = blockIdx.x * 4 + (threadIdx.x >> 6);
  const int lane = threadIdx.x & 63;
  const int tt = task >> 13;            // /NT
  const int i  = task & (NT - 1);
  const float* cur = part + (size_t)i * (TT * R) + (size_t)(t0 + tt) * R;
  const float* b = B480 + (size_t)rel_idx[i] * R;
  float v[8];
  float m = -3e38f;
  #pragma unroll
  for (int j = 0; j < 8; ++j) {
    const int r = lane + j * 64;
    float val = -1e9f;
    if (r < R) {
      const float c = cur[r];
      val = (c == 0.f) ? -1e9f : c * b[r];
      m = fmaxf(m, val);
    }
    v[j] = val;
  }
  #pragma unroll
  for (int o = 32; o; o >>= 1) m = fmaxf(m, __shfl_xor(m, o));
  float s = 0.f;
  #pragma unroll
  for (int j = 0; j < 8; ++j) {
    const int r = lane + j * 64;
    if (r < R) { v[j] = __expf(v[j] - m); s += v[j]; }
  }
  #pragma unroll
  for (int o = 32; o; o >>= 1) s += __shfl_xor(s, o);
  const float inv = 1.f / s;
  u16* arow = attn + (size_t)task * R;
  #pragma unroll
  for (int j = 0; j < 8; ++j) {
    const int r = lane + j * 64;
    if (r < R) arow[r] = f2b(v[j] * inv);
  }
}

// ---------------- fused gh GEMM + GRU gates --------------------------------
// Block: 128 rows x col-group cg (64 c-cols). Computes gh for virtual cols
// {cg*64..+64} u {256+..} u {512+..} (192 cols), then gates in epilogue.
// gi has bih folded everywhere and bhh folded for r,z chunks only.
__launch_bounds__(256)
__global__ void ghgates_k(const u16* __restrict__ hb, const u16* __restrict__ WhhT,
                          const float* __restrict__ bhh, const u16* __restrict__ gi,
                          float* __restrict__ h, u16* __restrict__ hb_out) {
  __shared__ __align__(16) u16 As[128 * 32];
  __shared__ __align__(16) u16 Bs[192 * 32];
  const int tid = threadIdx.x;
  const int lane = tid & 63;
  const int wv = tid >> 6;
  const int cg = blockIdx.x;            // 0..3
  const int m0 = blockIdx.y * 128;
  const int wr0 = wv * 32;
  const int fr = lane & 15;
  const int fq = lane >> 4;
  f32x4 acc[2][12] = {};

  for (int k0 = 0; k0 < H; k0 += 32) {
    __syncthreads();
    #pragma unroll
    for (int it = 0; it < 2; ++it) {     // A: 128 rows x 32 K = 512 chunks
      const int c = it * 256 + tid;
      const int row = c >> 2, cc = c & 3;
      gload_lds16(hb + (size_t)(m0 + row) * H + k0 + cc * 8,
                  &As[(it * 256 + wv * 64) * 8]);
    }
    #pragma unroll
    for (int it = 0; it < 3; ++it) {     // B: 192 vrows x 32 K = 768 chunks
      const int c = it * 256 + tid;
      const int vrow = c >> 2, cc = c & 3;
      const int col = (vrow >> 6) * 256 + cg * 64 + (vrow & 63);
      gload_lds16(WhhT + (size_t)col * H + k0 + cc * 8,
                  &Bs[(it * 256 + wv * 64) * 8]);
    }
    __syncthreads();
    bf16x8 a[2], b[12];
    #pragma unroll
    for (int mi = 0; mi < 2; ++mi)
      a[mi] = *(const bf16x8*)&As[(wr0 + mi * 16 + fr) * 32 + fq * 8];
    #pragma unroll
    for (int ni = 0; ni < 12; ++ni)
      b[ni] = *(const bf16x8*)&Bs[(ni * 16 + fr) * 32 + fq * 8];
    #pragma unroll
    for (int mi = 0; mi < 2; ++mi)
      #pragma unroll
      for (int ni = 0; ni < 12; ++ni)
        acc[mi][ni] = __builtin_amdgcn_mfma_f32_16x16x32_bf16(a[mi], b[ni], acc[mi][ni], 0, 0, 0);
  }

  #pragma unroll
  for (int nc = 0; nc < 4; ++nc) {
    const int c = cg * 64 + nc * 16 + fr;
    const float bn = bhh[512 + c];
    #pragma unroll
    for (int mi = 0; mi < 2; ++mi) {
      #pragma unroll
      for (int j = 0; j < 4; ++j) {
        const int row = m0 + wr0 + mi * 16 + fq * 4 + j;
        const size_t gb = (size_t)row * 768 + c;
        const float gir = b2f(gi[gb]);
        const float giz = b2f(gi[gb + 256]);
        const float gin = b2f(gi[gb + 512]);
        const float rg = 1.f / (1.f + __expf(-(gir + acc[mi][nc][j])));
        const float zg = 1.f / (1.f + __expf(-(giz + acc[mi][4 + nc][j])));
        const float ng = tanhf(gin + rg * (acc[mi][8 + nc][j] + bn));
        const size_t hi = (size_t)row * H + c;
        const float hn = (1.f - zg) * ng + zg * h[hi];
        h[hi] = hn;
        hb_out[hi] = f2b(hn);
      }
    }
  }
}

// ---------------- gathers / converts ---------------------------------------
__global__ void gather_sub_k(const float* __restrict__ pre, const int* __restrict__ sub,
                             u16* __restrict__ sb) {
  const int idx = blockIdx.x * 256 + threadIdx.x;   // NT*H
  const int i = idx >> 8, c = idx & 255;
  sb[idx] = f2b(pre[(size_t)sub[i] * H + c]);
}
__global__ void cvt_pre_k(const float* __restrict__ pre, u16* __restrict__ pb) {
  const int idx = blockIdx.x * 256 + threadIdx.x;   // NE*H
  pb[idx] = f2b(pre[idx]);
}

// ---------------- lhs = asub * G2[rel]; match partial sums -----------------
__global__ void lhsmatch_k(const int* __restrict__ rel_idx, const float* __restrict__ P,
                           const float* __restrict__ G2, const float* __restrict__ h,
                           const float* __restrict__ asub, u16* __restrict__ lhs,
                           float* __restrict__ mpart) {
  const int tid = threadIdx.x;
  const int blk = blockIdx.x;        // 2048 blocks, 1024 elems each
  float local = 0.f;
  #pragma unroll
  for (int u = 0; u < 4; ++u) {
    const int idx = blk * 1024 + u * 256 + tid;
    const int i = idx >> 8, c = idx & 255;
    const int rel = rel_idx[i];
    const float d = P[(size_t)rel * H + c] - h[idx];
    local += d * d;
    lhs[idx] = f2b(asub[idx] * G2[(size_t)rel * H + c]);
  }
  #pragma unroll
  for (int o = 32; o; o >>= 1) local += __shfl_down(local, o);
  __shared__ float red[4];
  if ((tid & 63) == 0) red[tid >> 6] = local;
  __syncthreads();
  if (tid == 0) mpart[blk] = red[0] + red[1] + red[2] + red[3];
}

// ---------------- pos_i = dot(lhs[i], alignedT[obj[i]]) --------------------
__global__ void pos_k(const u16* __restrict__ lhs, const u16* __restrict__ alT,
                      const int* __restrict__ obj, float* __restrict__ pos) {
  const int row = blockIdx.x * 4 + (threadIdx.x >> 6);
  const int lane = threadIdx.x & 63;
  const u16* a = lhs + (size_t)row * H;
  const u16* b = alT + (size_t)obj[row] * H;
  float s = 0.f;
  #pragma unroll
  for (int j = 0; j < 4; ++j) {
    const int c = lane + j * 64;
    s += b2f(a[c]) * b2f(b[c]);
  }
  #pragma unroll
  for (int o = 32; o; o >>= 1) s += __shfl_down(s, o);
  if (lane == 0) pos[row] = s;
}

// ---------------- final scalar reduction -----------------------------------
__global__ void finalize_k(const float* __restrict__ mp, const float* __restrict__ sp,
                           const float* __restrict__ pos, float* __restrict__ out) {
  const int tid = threadIdx.x;
  float s1 = 0.f, s2 = 0.f, s3 = 0.f;
  for (int i = tid; i < 2048; i += 256) s1 += mp[i];
  for (int i = tid; i < 11520; i += 256) s2 += sp[i];
  for (int i = tid; i < 8192; i += 256) s3 += pos[i];
  #pragma unroll
  for (int o = 32; o; o >>= 1) {
    s1 += __shfl_down(s1, o); s2 += __shfl_down(s2, o); s3 += __shfl_down(s3, o);
  }
  __shared__ float r1[4], r2[4], r3[4];
  if ((tid & 63) == 0) { r1[tid >> 6] = s1; r2[tid >> 6] = s2; r3[tid >> 6] = s3; }
  __syncthreads();
  if (tid == 0) {
    const float a = r1[0] + r1[1] + r1[2] + r1[3];
    const float b = r2[0] + r2[1] + r2[2] + r2[3];
    const float c = r3[0] + r3[1] + r3[2] + r3[3];
    out[0] = a / 2097152.f;               // mean over 8192*256
    out[1] = (b - c) / 188416000.f;       // (softplus sum - pos sum)/(8192*23000)
  }
}

// ---------------- bf16 MFMA GEMM: C[M,N] = A[M,K] @ Bt[N,K]^T --------------
template <int MODE>
__launch_bounds__(256)
__global__ void gemm_k(const u16* __restrict__ A, const u16* __restrict__ Bt,
                       const float* __restrict__ bias,
                       float* __restrict__ Cf, u16* __restrict__ Cb,
                       int M, int N, int K,
                       float* __restrict__ out2, float* __restrict__ part) {
  __shared__ __align__(16) u16 As[128 * 32];
  __shared__ __align__(16) u16 Bs[128 * 32];
  __shared__ float red[4];
  const int tid = threadIdx.x;
  const int lane = tid & 63;
  const int wv = tid >> 6;
  const int m0 = blockIdx.y * 128;
  const int n0 = blockIdx.x * 128;
  const int wm = (wv >> 1) * 64;
  const int wn = (wv & 1) * 64;
  const int fr = lane & 15;
  const int fq = lane >> 4;
  f32x4 acc[4][4] = {};

  for (int k0 = 0; k0 < K; k0 += 32) {
    __syncthreads();
    #pragma unroll
    for (int it = 0; it < 2; ++it) {
      const int c = it * 256 + tid;       // 16B chunk id, 512 per tile
      const int row = c >> 2;
      const int cc = c & 3;
      int gr = m0 + row; gr = gr < M ? gr : M - 1;
      gload_lds16(A + (size_t)gr * K + k0 + cc * 8, &As[(it * 256 + wv * 64) * 8]);
      int nr = n0 + row; nr = nr < N ? nr : N - 1;
      gload_lds16(Bt + (size_t)nr * K + k0 + cc * 8, &Bs[(it * 256 + wv * 64) * 8]);
    }
    __syncthreads();
    bf16x8 a[4], b[4];
    #pragma unroll
    for (int mi = 0; mi < 4; ++mi)
      a[mi] = *(const bf16x8*)&As[(wm + mi * 16 + fr) * 32 + fq * 8];
    #pragma unroll
    for (int ni = 0; ni < 4; ++ni)
      b[ni] = *(const bf16x8*)&Bs[(wn + ni * 16 + fr) * 32 + fq * 8];
    #pragma unroll
    for (int mi = 0; mi < 4; ++mi)
      #pragma unroll
      for (int ni = 0; ni < 4; ++ni)
        acc[mi][ni] = __builtin_amdgcn_mfma_f32_16x16x32_bf16(a[mi], b[ni], acc[mi][ni], 0, 0, 0);
  }

  float local = 0.f;
  #pragma unroll
  for (int mi = 0; mi < 4; ++mi) {
    #pragma unroll
    for (int ni = 0; ni < 4; ++ni) {
      const int col = n0 + wn + ni * 16 + fr;
      float bv = 0.f;
      if (MODE == 0 && bias != nullptr && col < N) bv = bias[col];
      const f32x4 v = acc[mi][ni];
      #pragma unroll
      for (int j = 0; j < 4; ++j) {
        const int rowm = m0 + wm + mi * 16 + fq * 4 + j;
        if (rowm < M && col < N) {
          if (MODE == 0) {
            const float val = v[j] + bv;
            if (Cf) Cf[(size_t)rowm * N + col] = val;
            if (Cb) Cb[(size_t)rowm * N + col] = f2b(val);
          } else {
            const float s = v[j];
            const float sig = 1.f / (1.f + __expf(-s));
            out2[(size_t)rowm * N + col] = sig;
            const float om = 1.f - sig;
            local += (om > 0.f) ? -__logf(om) : s;
          }
        }
      }
    }
  }
  if (MODE == 1) {
    #pragma unroll
    for (int o = 32; o; o >>= 1) local += __shfl_down(local, o);
    if (lane == 0) red[wv] = local;
    __syncthreads();
    if (tid == 0) part[blockIdx.y * gridDim.x + blockIdx.x] = red[0] + red[1] + red[2] + red[3];
  }
}

extern "C" void kernel_launch(void* const* d_in, const int* in_sizes, int n_in,
                              void* d_out, int out_size, void* d_ws, size_t ws_size,
                              hipStream_t stream) {
  const float* pre_emb = (const float*)d_in[0];
  const float* r_emb   = (const float*)d_in[1];
  const float* part_e  = (const float*)d_in[2];
  const int*   sub_idx = (const int*)d_in[3];
  const int*   rel_idx = (const int*)d_in[4];
  const int*   obj_idx = (const int*)d_in[5];
  const float* Wm1 = (const float*)d_in[7];  const float* bm1 = (const float*)d_in[8];
  const float* Wm2 = (const float*)d_in[9];  const float* bm2 = (const float*)d_in[10];
  const float* Wattn = (const float*)d_in[11]; const float* battn = (const float*)d_in[12];
  const float* Wh1 = (const float*)d_in[13]; const float* bh1 = (const float*)d_in[14];
  const float* Wh2 = (const float*)d_in[15]; const float* bh2 = (const float*)d_in[16];
  const float* Walign = (const float*)d_in[17]; const float* balign = (const float*)d_in[18];
  const float* Wih = (const float*)d_in[19]; const float* Whh = (const float*)d_in[20];
  const float* bih = (const float*)d_in[21]; const float* bhh = (const float*)d_in[22];
  float* out = (float*)d_out;

  char* w = (char*)d_ws;
  size_t off = 0;
  auto alloc = [&](size_t bytes) -> void* {
    off = (off + 255) & ~(size_t)255;
    void* p = w + off;
    off += bytes;
    return p;
  };
  float* hidden = (float*)alloc((size_t)R * 512 * 4);
  float* mapped = (float*)alloc((size_t)R * H * 4);
  float* t1     = (float*)alloc((size_t)R * H * 4);
  float* B480   = (float*)alloc((size_t)R * R * 4);
  float* MW     = (float*)alloc((size_t)R * 768 * 4);
  float* p1     = (float*)alloc((size_t)R * H * 4);
  float* P      = (float*)alloc((size_t)R * H * 4);
  float* PW     = (float*)alloc((size_t)R * 768 * 4);
  float* G2     = (float*)alloc((size_t)R * H * 4);
  u16* MWT      = (u16*)alloc((size_t)768 * R * 2);
  u16* WhhT     = (u16*)alloc((size_t)768 * H * 2);
  u16* WalignT  = (u16*)alloc((size_t)H * H * 2);
  float* bsum   = (float*)alloc(768 * 4);
  float* hbuf   = (float*)alloc((size_t)NT * H * 4);
  u16* hb0      = (u16*)alloc((size_t)NT * H * 2);
  u16* hb1      = (u16*)alloc((size_t)NT * H * 2);
  float* asub   = (float*)alloc((size_t)NT * H * 4);
  u16* lhs_b    = (u16*)alloc((size_t)NT * H * 2);
  u16* sub_b    = (u16*)alloc((size_t)NT * H * 2);
  u16* pre_b    = (u16*)alloc((size_t)NE * H * 2);
  u16* alT      = (u16*)alloc((size_t)NE * H * 2);
  float* mpart  = (float*)alloc(2048 * 4);
  float* spart  = (float*)alloc(11520 * 4);
  float* posar  = (float*)alloc(8192 * 4);
  const size_t fixed_end = off;

  // chunked scan buffers: try all 10 steps at once, fall back to 1
  int chunkT = TT;
  u16 *attn_all = nullptr, *gi_all = nullptr;
  for (;;) {
    off = fixed_end;
    attn_all = (u16*)alloc((size_t)chunkT * NT * R * 2);
    gi_all   = (u16*)alloc((size_t)chunkT * NT * 768 * 2);
    if (off <= ws_size) break;
    if (chunkT == 1) return;            // workspace insufficient; fail visibly
    chunkT = 1;
  }

  auto cdiv = [](int a, int b) { return (a + b - 1) / b; };

  init_k<<<NT, 256, 0, stream>>>(hbuf, (unsigned int*)hb0);

  // rank-480 precompute (exact f32)
  sgemm_k<<<cdiv(R * 512, 256), 256, 0, stream>>>(r_emb, Wm1, bm1, nullptr, 1.f, hidden, R, 512, H, 0);
  sgemm_k<<<cdiv(R * H, 256), 256, 0, stream>>>(hidden, Wm2, bm2, nullptr, 1.f, mapped, R, H, 512, 0);
  sgemm_k<<<cdiv(R * H, 256), 256, 0, stream>>>(mapped, Wattn, battn, nullptr, 1.f, t1, R, H, H, 0);
  sgemm_k<<<cdiv(R * R, 256), 256, 0, stream>>>(t1, mapped, nullptr, nullptr, 1.f, B480, R, R, H, 1);
  sgemm_k<<<cdiv(R * 768, 256), 256, 0, stream>>>(mapped, Wih, nullptr, nullptr, 1.f, MW, R, 768, H, 0);
  sgemm_k<<<cdiv(R * H, 256), 256, 0, stream>>>(mapped, Wh1, bh1, nullptr, 1.f, p1, R, H, H, 0);
  sgemm_k<<<cdiv(R * H, 256), 256, 0, stream>>>(p1, Wh2, bh2, mapped, 0.1f, P, R, H, H, 0);
  sgemm_k<<<cdiv(R * 768, 256), 256, 0, stream>>>(P, Whh, bhh, nullptr, 1.f, PW, R, 768, H, 0);
  g2_k<<<cdiv(R * H, 256), 256, 0, stream>>>(MW, PW, P, bih, G2);
  transpose_w_k<<<cdiv(R * 768, 256), 256, 0, stream>>>(MW, MWT, R, 768);
  transpose_w_k<<<cdiv(H * 768, 256), 256, 0, stream>>>(Whh, WhhT, H, 768);
  transpose_w_k<<<cdiv(H * H, 256), 256, 0, stream>>>(Walign, WalignT, H, H);
  bsum_k<<<3, 256, 0, stream>>>(bih, bhh, bsum);

  // scan: batched softmax + batched gi GEMM, then fused gh+gates per step
  u16* hcur = hb0;
  u16* hnxt = hb1;
  for (int t0 = 0; t0 < TT; t0 += chunkT) {
    softmax_all_k<<<chunkT * (NT / 4), 256, 0, stream>>>(part_e, B480, rel_idx, attn_all, t0);
    gemm_k<0><<<dim3(6, chunkT * (NT / 128)), 256, 0, stream>>>(
        attn_all, MWT, bsum, nullptr, gi_all, chunkT * NT, 768, R, nullptr, nullptr);
    for (int tt = 0; tt < chunkT; ++tt) {
      ghgates_k<<<dim3(4, NT / 128), 256, 0, stream>>>(
          hcur, WhhT, bhh, gi_all + (size_t)tt * NT * 768, hbuf, hnxt);
      u16* tmp = hcur; hcur = hnxt; hnxt = tmp;
    }
  }

  // aligned sub + lhs + match partials
  gather_sub_k<<<NT, 256, 0, stream>>>(pre_emb, sub_idx, sub_b);
  gemm_k<0><<<dim3(2, 64), 256, 0, stream>>>(sub_b, WalignT, balign, asub, nullptr, NT, H, H, nullptr, nullptr);
  lhsmatch_k<<<2048, 256, 0, stream>>>(rel_idx, P, G2, hbuf, asub, lhs_b, mpart);

  // aligned entity table (bf16, [NE][H] = Bt layout for final GEMM)
  cvt_pre_k<<<NE, 256, 0, stream>>>(pre_emb, pre_b);
  gemm_k<0><<<dim3(2, 180), 256, 0, stream>>>(pre_b, WalignT, balign, nullptr, alT, NE, H, H, nullptr, nullptr);

  // final score GEMM with sigmoid + softplus epilogue
  gemm_k<1><<<dim3(180, 64), 256, 0, stream>>>(lhs_b, alT, nullptr, nullptr, nullptr, NT, NE, H, out + 2, spart);

  // pos + final scalars
  pos_k<<<2048, 256, 0, stream>>>(lhs_b, alT, obj_idx, posar);
  finalize_k<<<1, 256, 0, stream>>>(mpart, spart, posar, out);
}

// Round 3
// 1819.593 us; speedup vs baseline: 1.1769x; 1.0568x over previous
//
#include <hip/hip_runtime.h>
#include <hip/hip_bf16.h>
#include <stdint.h>

#define DEV __device__ __forceinline__

typedef unsigned short u16;
typedef __attribute__((ext_vector_type(8))) short bf16x8;
typedef __attribute__((ext_vector_type(4))) float f32x4;
typedef __attribute__((ext_vector_type(4))) unsigned short u16x4;

constexpr int H  = 256;
constexpr int R  = 480;
constexpr int NE = 23000;
constexpr int NT = 8192;
constexpr int TT = 10;

DEV u16 f2b(float f) {
  union { float f; unsigned u; } x; x.f = f;
  unsigned u = x.u;
  return (u16)((u + 0x7fffu + ((u >> 16) & 1u)) >> 16);
}
DEV float b2f(u16 h) {
  union { unsigned u; float f; } x; x.u = ((unsigned)h) << 16;
  return x.f;
}

DEV void gload_lds16(const u16* g, u16* lds) {
  __builtin_amdgcn_global_load_lds(
      (const __attribute__((address_space(1))) unsigned int*)g,
      (__attribute__((address_space(3))) unsigned int*)lds, 16, 0, 0);
}

// ---------------- init: zero h (f32) and h_b0 (bf16) ----------------
__global__ void init_k(float* __restrict__ h, unsigned int* __restrict__ hb) {
  const int idx = blockIdx.x * 256 + threadIdx.x;   // NT*H threads
  h[idx] = 0.f;
  if (idx < (NT * H) / 2) hb[idx] = 0u;
}

// ---------------- generic small f32 GEMM: C = scale*(A@W + bias) + add ----
__global__ void sgemm_k(const float* __restrict__ A, const float* __restrict__ W,
                        const float* __restrict__ bias, const float* __restrict__ add,
                        float scale, float* __restrict__ C,
                        int M, int N, int K, int transW) {
  const int idx = blockIdx.x * 256 + threadIdx.x;
  if (idx >= M * N) return;
  const int i = idx / N, j = idx % N;
  float s = bias ? bias[j] : 0.f;
  const float* a = A + (size_t)i * K;
  if (!transW) {
    for (int k = 0; k < K; ++k) s += a[k] * W[(size_t)k * N + j];
  } else {
    const float* w = W + (size_t)j * K;
    for (int k = 0; k < K; ++k) s += a[k] * w[k];
  }
  C[idx] = scale * s + (add ? add[idx] : 0.f);
}

// ---------------- transpose f32 -> bf16: W[K][Nn] -> Wt[Nn][K] -------------
__global__ void transpose_w_k(const float* __restrict__ W, u16* __restrict__ Wt,
                              int K, int Nn) {
  const int idx = blockIdx.x * 256 + threadIdx.x;
  if (idx >= K * Nn) return;
  const int k = idx / Nn, n = idx % Nn;
  Wt[(size_t)n * K + k] = f2b(W[idx]);
}

// ---------------- combined bias: bih + bhh for r,z chunks; bih for n -------
__global__ void bsum_k(const float* __restrict__ bih, const float* __restrict__ bhh,
                       float* __restrict__ bs) {
  const int c = blockIdx.x * 256 + threadIdx.x;   // 768
  if (c < 768) bs[c] = bih[c] + (c < 512 ? bhh[c] : 0.f);
}

// ---------------- G2 = GRUcell(x=mapped, h=P) per rel row ------------------
__global__ void g2_k(const float* __restrict__ MW, const float* __restrict__ PW,
                     const float* __restrict__ P, const float* __restrict__ bih,
                     float* __restrict__ G2) {
  const int idx = blockIdx.x * 256 + threadIdx.x;   // 480*256
  if (idx >= R * H) return;
  const int r = idx >> 8, c = idx & 255;
  const float* mw = MW + (size_t)r * 768;
  const float* pw = PW + (size_t)r * 768;
  const float ir = mw[c] + bih[c];
  const float iz = mw[c + 256] + bih[c + 256];
  const float in_ = mw[c + 512] + bih[c + 512];
  const float rr = 1.f / (1.f + __expf(-(ir + pw[c])));
  const float z  = 1.f / (1.f + __expf(-(iz + pw[c + 256])));
  const float n  = tanhf(in_ + rr * pw[c + 512]);
  G2[idx] = (1.f - z) * n + z * P[idx];
}

// ---------------- masked softmax for all steps -----------------------------
__global__ void softmax_all_k(const float* __restrict__ part, const float* __restrict__ B480,
                              const int* __restrict__ rel_idx, u16* __restrict__ attn,
                              int t0) {
  const int task = blockIdx.x * 4 + (threadIdx.x >> 6);
  const int lane = threadIdx.x & 63;
  const int tt = task >> 13;            // /NT
  const int i  = task & (NT - 1);
  const float* cur = part + (size_t)i * (TT * R) + (size_t)(t0 + tt) * R;
  const float* b = B480 + (size_t)rel_idx[i] * R;
  float v[8];
  float m = -3e38f;
  #pragma unroll
  for (int j = 0; j < 8; ++j) {
    const int r = lane + j * 64;
    float val = -1e9f;
    if (r < R) {
      const float c = cur[r];
      val = (c == 0.f) ? -1e9f : c * b[r];
      m = fmaxf(m, val);
    }
    v[j] = val;
  }
  #pragma unroll
  for (int o = 32; o; o >>= 1) m = fmaxf(m, __shfl_xor(m, o));
  float s = 0.f;
  #pragma unroll
  for (int j = 0; j < 8; ++j) {
    const int r = lane + j * 64;
    if (r < R) { v[j] = __expf(v[j] - m); s += v[j]; }
  }
  #pragma unroll
  for (int o = 32; o; o >>= 1) s += __shfl_xor(s, o);
  const float inv = 1.f / s;
  u16* arow = attn + (size_t)task * R;
  #pragma unroll
  for (int j = 0; j < 8; ++j) {
    const int r = lane + j * 64;
    if (r < R) arow[r] = f2b(v[j] * inv);
  }
}

// ---------------- fused gh GEMM + GRU gates --------------------------------
// Swapped-operand MFMA: lane owns row=..+fr, cols=..+fq*4+{0..3} (vector I/O).
__launch_bounds__(256)
__global__ void ghgates_k(const u16* __restrict__ hb, const u16* __restrict__ WhhT,
                          const float* __restrict__ bhh, const u16* __restrict__ gi,
                          float* __restrict__ h, u16* __restrict__ hb_out) {
  __shared__ __align__(16) u16 As[128 * 32];
  __shared__ __align__(16) u16 Bs[192 * 32];
  const int tid = threadIdx.x;
  const int lane = tid & 63;
  const int wv = tid >> 6;
  const int cg = blockIdx.x;            // 0..3
  const int m0 = blockIdx.y * 128;
  const int wr0 = wv * 32;
  const int fr = lane & 15;
  const int fq = lane >> 4;
  f32x4 acc[2][12] = {};

  for (int k0 = 0; k0 < H; k0 += 32) {
    __syncthreads();
    #pragma unroll
    for (int it = 0; it < 2; ++it) {     // A: 128 rows x 32 K
      const int c = it * 256 + tid;
      const int row = c >> 2, cc = c & 3;
      gload_lds16(hb + (size_t)(m0 + row) * H + k0 + cc * 8,
                  &As[(it * 256 + wv * 64) * 8]);
    }
    #pragma unroll
    for (int it = 0; it < 3; ++it) {     // B: 192 vrows x 32 K
      const int c = it * 256 + tid;
      const int vrow = c >> 2, cc = c & 3;
      const int col = (vrow >> 6) * 256 + cg * 64 + (vrow & 63);
      gload_lds16(WhhT + (size_t)col * H + k0 + cc * 8,
                  &Bs[(it * 256 + wv * 64) * 8]);
    }
    __syncthreads();
    bf16x8 a[2], b[12];
    #pragma unroll
    for (int mi = 0; mi < 2; ++mi)
      a[mi] = *(const bf16x8*)&As[(wr0 + mi * 16 + fr) * 32 + fq * 8];
    #pragma unroll
    for (int ni = 0; ni < 12; ++ni)
      b[ni] = *(const bf16x8*)&Bs[(ni * 16 + fr) * 32 + fq * 8];
    #pragma unroll
    for (int mi = 0; mi < 2; ++mi)
      #pragma unroll
      for (int ni = 0; ni < 12; ++ni)
        acc[mi][ni] = __builtin_amdgcn_mfma_f32_16x16x32_bf16(b[ni], a[mi], acc[mi][ni], 0, 0, 0);
  }

  #pragma unroll
  for (int nc = 0; nc < 4; ++nc) {
    const int c = cg * 64 + nc * 16 + fq * 4;
    const f32x4 bn = *(const f32x4*)&bhh[512 + c];
    #pragma unroll
    for (int mi = 0; mi < 2; ++mi) {
      const int row = m0 + wr0 + mi * 16 + fr;
      const size_t gb = (size_t)row * 768 + c;
      const u16x4 g_r = *(const u16x4*)&gi[gb];
      const u16x4 g_z = *(const u16x4*)&gi[gb + 256];
      const u16x4 g_n = *(const u16x4*)&gi[gb + 512];
      const size_t hi = (size_t)row * H + c;
      const f32x4 hv = *(const f32x4*)&h[hi];
      f32x4 hn;
      u16x4 hb4;
      #pragma unroll
      for (int j = 0; j < 4; ++j) {
        const float rg = 1.f / (1.f + __expf(-(b2f(g_r[j]) + acc[mi][nc][j])));
        const float zg = 1.f / (1.f + __expf(-(b2f(g_z[j]) + acc[mi][4 + nc][j])));
        const float ng = tanhf(b2f(g_n[j]) + rg * (acc[mi][8 + nc][j] + bn[j]));
        hn[j] = (1.f - zg) * ng + zg * hv[j];
        hb4[j] = f2b(hn[j]);
      }
      *(f32x4*)&h[hi] = hn;
      *(u16x4*)&hb_out[hi] = hb4;
    }
  }
}

// ---------------- gathers / converts (vectorized) --------------------------
__global__ void gather_sub_k(const float* __restrict__ pre, const int* __restrict__ sub,
                             u16* __restrict__ sb) {
  const int q = blockIdx.x * 256 + threadIdx.x;   // NT*H/4
  const int i = q >> 6, c = (q & 63) * 4;
  const f32x4 v = *(const f32x4*)&pre[(size_t)sub[i] * H + c];
  u16x4 o;
  #pragma unroll
  for (int j = 0; j < 4; ++j) o[j] = f2b(v[j]);
  *(u16x4*)&sb[(size_t)q * 4] = o;
}
__global__ void cvt_pre_k(const float* __restrict__ pre, u16* __restrict__ pb) {
  const int q = blockIdx.x * 256 + threadIdx.x;   // NE*H/4
  const f32x4 v = *(const f32x4*)&pre[(size_t)q * 4];
  u16x4 o;
  #pragma unroll
  for (int j = 0; j < 4; ++j) o[j] = f2b(v[j]);
  *(u16x4*)&pb[(size_t)q * 4] = o;
}

// ---------------- lhs = asub * G2[rel]; match partial sums -----------------
__global__ void lhsmatch_k(const int* __restrict__ rel_idx, const float* __restrict__ P,
                           const float* __restrict__ G2, const float* __restrict__ h,
                           const float* __restrict__ asub, u16* __restrict__ lhs,
                           float* __restrict__ mpart) {
  const int tid = threadIdx.x;
  const int blk = blockIdx.x;        // 512 blocks, 1024 quads each
  float local = 0.f;
  #pragma unroll
  for (int u = 0; u < 4; ++u) {
    const int q = blk * 1024 + u * 256 + tid;
    const int i = q >> 6;
    const int c = (q & 63) * 4;
    const int rel = rel_idx[i];
    const f32x4 Pv = *(const f32x4*)&P[(size_t)rel * H + c];
    const f32x4 Gv = *(const f32x4*)&G2[(size_t)rel * H + c];
    const f32x4 hv = *(const f32x4*)&h[(size_t)i * H + c];
    const f32x4 av = *(const f32x4*)&asub[(size_t)i * H + c];
    u16x4 o;
    #pragma unroll
    for (int j = 0; j < 4; ++j) {
      const float d = Pv[j] - hv[j];
      local += d * d;
      o[j] = f2b(av[j] * Gv[j]);
    }
    *(u16x4*)&lhs[(size_t)i * H + c] = o;
  }
  #pragma unroll
  for (int o = 32; o; o >>= 1) local += __shfl_down(local, o);
  __shared__ float red[4];
  if ((tid & 63) == 0) red[tid >> 6] = local;
  __syncthreads();
  if (tid == 0) mpart[blk] = red[0] + red[1] + red[2] + red[3];
}

// ---------------- pos_i = dot(lhs[i], alignedT[obj[i]]) --------------------
__global__ void pos_k(const u16* __restrict__ lhs, const u16* __restrict__ alT,
                      const int* __restrict__ obj, float* __restrict__ pos) {
  const int row = blockIdx.x * 4 + (threadIdx.x >> 6);
  const int lane = threadIdx.x & 63;
  const u16x4 av = *(const u16x4*)&lhs[(size_t)row * H + lane * 4];
  const u16x4 bv = *(const u16x4*)&alT[(size_t)obj[row] * H + lane * 4];
  float s = 0.f;
  #pragma unroll
  for (int j = 0; j < 4; ++j) s += b2f(av[j]) * b2f(bv[j]);
  #pragma unroll
  for (int o = 32; o; o >>= 1) s += __shfl_down(s, o);
  if (lane == 0) pos[row] = s;
}

// ---------------- final scalar reduction -----------------------------------
__global__ void finalize_k(const float* __restrict__ mp, const float* __restrict__ sp,
                           const float* __restrict__ pos, float* __restrict__ out) {
  const int tid = threadIdx.x;
  float s1 = 0.f, s2 = 0.f, s3 = 0.f;
  for (int i = tid; i < 512; i += 256) s1 += mp[i];
  for (int i = tid; i < 11520; i += 256) s2 += sp[i];
  for (int i = tid; i < 8192; i += 256) s3 += pos[i];
  #pragma unroll
  for (int o = 32; o; o >>= 1) {
    s1 += __shfl_down(s1, o); s2 += __shfl_down(s2, o); s3 += __shfl_down(s3, o);
  }
  __shared__ float r1[4], r2[4], r3[4];
  if ((tid & 63) == 0) { r1[tid >> 6] = s1; r2[tid >> 6] = s2; r3[tid >> 6] = s3; }
  __syncthreads();
  if (tid == 0) {
    const float a = r1[0] + r1[1] + r1[2] + r1[3];
    const float b = r2[0] + r2[1] + r2[2] + r2[3];
    const float c = r3[0] + r3[1] + r3[2] + r3[3];
    out[0] = a / 2097152.f;               // mean over 8192*256
    out[1] = (b - c) / 188416000.f;       // (softplus sum - pos sum)/(8192*23000)
  }
}

// ---------------- bf16 MFMA GEMM: C[M,N] = A[M,K] @ Bt[N,K]^T --------------
// Swapped-operand MFMA: per-lane output is row=..+fr, cols=..+fq*4+{0..3}
// -> float4 / 8B-bf16 vector stores. XCD-swizzled block mapping.
template <int MODE>
__launch_bounds__(256)
__global__ void gemm_k(const u16* __restrict__ A, const u16* __restrict__ Bt,
                       const float* __restrict__ bias,
                       float* __restrict__ Cf, u16* __restrict__ Cb,
                       int M, int N, int K,
                       float* __restrict__ out2, float* __restrict__ part) {
  __shared__ __align__(16) u16 As[128 * 32];
  __shared__ __align__(16) u16 Bs[128 * 32];
  __shared__ float red[4];
  const int tid = threadIdx.x;
  const int lane = tid & 63;
  const int wv = tid >> 6;
  // bijective XCD swizzle (all grids are %8==0)
  const int nbx = gridDim.x;
  int flat = blockIdx.y * nbx + blockIdx.x;
  const int nwg = nbx * gridDim.y;
  if ((nwg & 7) == 0) flat = (flat & 7) * (nwg >> 3) + (flat >> 3);
  const int bx = flat % nbx;
  const int by = flat / nbx;
  const int m0 = by * 128;
  const int n0 = bx * 128;
  const int wm = (wv >> 1) * 64;
  const int wn = (wv & 1) * 64;
  const int fr = lane & 15;
  const int fq = lane >> 4;
  f32x4 acc[4][4] = {};

  for (int k0 = 0; k0 < K; k0 += 32) {
    __syncthreads();
    #pragma unroll
    for (int it = 0; it < 2; ++it) {
      const int c = it * 256 + tid;       // 16B chunk id, 512 per tile
      const int row = c >> 2;
      const int cc = c & 3;
      int gr = m0 + row; gr = gr < M ? gr : M - 1;
      gload_lds16(A + (size_t)gr * K + k0 + cc * 8, &As[(it * 256 + wv * 64) * 8]);
      int nr = n0 + row; nr = nr < N ? nr : N - 1;
      gload_lds16(Bt + (size_t)nr * K + k0 + cc * 8, &Bs[(it * 256 + wv * 64) * 8]);
    }
    __syncthreads();
    bf16x8 a[4], b[4];
    #pragma unroll
    for (int mi = 0; mi < 4; ++mi)
      a[mi] = *(const bf16x8*)&As[(wm + mi * 16 + fr) * 32 + fq * 8];
    #pragma unroll
    for (int ni = 0; ni < 4; ++ni)
      b[ni] = *(const bf16x8*)&Bs[(wn + ni * 16 + fr) * 32 + fq * 8];
    #pragma unroll
    for (int mi = 0; mi < 4; ++mi)
      #pragma unroll
      for (int ni = 0; ni < 4; ++ni)
        acc[mi][ni] = __builtin_amdgcn_mfma_f32_16x16x32_bf16(b[ni], a[mi], acc[mi][ni], 0, 0, 0);
  }

  float local = 0.f;
  #pragma unroll
  for (int mi = 0; mi < 4; ++mi) {
    const int rowm = m0 + wm + mi * 16 + fr;
    #pragma unroll
    for (int ni = 0; ni < 4; ++ni) {
      const int col = n0 + wn + ni * 16 + fq * 4;   // quad base, col%4==0
      if (rowm < M && col < N) {
        f32x4 v = acc[mi][ni];
        if (MODE == 0) {
          if (bias != nullptr) {
            const f32x4 bv = *(const f32x4*)&bias[col];
            #pragma unroll
            for (int j = 0; j < 4; ++j) v[j] += bv[j];
          }
          if (Cf) *(f32x4*)&Cf[(size_t)rowm * N + col] = v;
          if (Cb) {
            u16x4 o;
            #pragma unroll
            for (int j = 0; j < 4; ++j) o[j] = f2b(v[j]);
            *(u16x4*)&Cb[(size_t)rowm * N + col] = o;
          }
        } else {
          f32x4 sg;
          #pragma unroll
          for (int j = 0; j < 4; ++j) {
            const float s = v[j];
            const float sig = 1.f / (1.f + __expf(-s));
            sg[j] = sig;
            const float om = 1.f - sig;
            local += (om > 0.f) ? -__logf(om) : s;
          }
          *(f32x4*)&out2[(size_t)rowm * N + col] = sg;
        }
      }
    }
  }
  if (MODE == 1) {
    #pragma unroll
    for (int o = 32; o; o >>= 1) local += __shfl_down(local, o);
    if (lane == 0) red[wv] = local;
    __syncthreads();
    if (tid == 0) part[blockIdx.y * gridDim.x + blockIdx.x] = red[0] + red[1] + red[2] + red[3];
  }
}

extern "C" void kernel_launch(void* const* d_in, const int* in_sizes, int n_in,
                              void* d_out, int out_size, void* d_ws, size_t ws_size,
                              hipStream_t stream) {
  const float* pre_emb = (const float*)d_in[0];
  const float* r_emb   = (const float*)d_in[1];
  const float* part_e  = (const float*)d_in[2];
  const int*   sub_idx = (const int*)d_in[3];
  const int*   rel_idx = (const int*)d_in[4];
  const int*   obj_idx = (const int*)d_in[5];
  const float* Wm1 = (const float*)d_in[7];  const float* bm1 = (const float*)d_in[8];
  const float* Wm2 = (const float*)d_in[9];  const float* bm2 = (const float*)d_in[10];
  const float* Wattn = (const float*)d_in[11]; const float* battn = (const float*)d_in[12];
  const float* Wh1 = (const float*)d_in[13]; const float* bh1 = (const float*)d_in[14];
  const float* Wh2 = (const float*)d_in[15]; const float* bh2 = (const float*)d_in[16];
  const float* Walign = (const float*)d_in[17]; const float* balign = (const float*)d_in[18];
  const float* Wih = (const float*)d_in[19]; const float* Whh = (const float*)d_in[20];
  const float* bih = (const float*)d_in[21]; const float* bhh = (const float*)d_in[22];
  float* out = (float*)d_out;

  char* w = (char*)d_ws;
  size_t off = 0;
  auto alloc = [&](size_t bytes) -> void* {
    off = (off + 255) & ~(size_t)255;
    void* p = w + off;
    off += bytes;
    return p;
  };
  float* hidden = (float*)alloc((size_t)R * 512 * 4);
  float* mapped = (float*)alloc((size_t)R * H * 4);
  float* t1     = (float*)alloc((size_t)R * H * 4);
  float* B480   = (float*)alloc((size_t)R * R * 4);
  float* MW     = (float*)alloc((size_t)R * 768 * 4);
  float* p1     = (float*)alloc((size_t)R * H * 4);
  float* P      = (float*)alloc((size_t)R * H * 4);
  float* PW     = (float*)alloc((size_t)R * 768 * 4);
  float* G2     = (float*)alloc((size_t)R * H * 4);
  u16* MWT      = (u16*)alloc((size_t)768 * R * 2);
  u16* WhhT     = (u16*)alloc((size_t)768 * H * 2);
  u16* WalignT  = (u16*)alloc((size_t)H * H * 2);
  float* bsum   = (float*)alloc(768 * 4);
  float* hbuf   = (float*)alloc((size_t)NT * H * 4);
  u16* hb0      = (u16*)alloc((size_t)NT * H * 2);
  u16* hb1      = (u16*)alloc((size_t)NT * H * 2);
  float* asub   = (float*)alloc((size_t)NT * H * 4);
  u16* lhs_b    = (u16*)alloc((size_t)NT * H * 2);
  u16* sub_b    = (u16*)alloc((size_t)NT * H * 2);
  u16* pre_b    = (u16*)alloc((size_t)NE * H * 2);
  u16* alT      = (u16*)alloc((size_t)NE * H * 2);
  float* mpart  = (float*)alloc(512 * 4);
  float* spart  = (float*)alloc(11520 * 4);
  float* posar  = (float*)alloc(8192 * 4);
  const size_t fixed_end = off;

  // chunked scan buffers: try all 10 steps at once, fall back to 1
  int chunkT = TT;
  u16 *attn_all = nullptr, *gi_all = nullptr;
  for (;;) {
    off = fixed_end;
    attn_all = (u16*)alloc((size_t)chunkT * NT * R * 2);
    gi_all   = (u16*)alloc((size_t)chunkT * NT * 768 * 2);
    if (off <= ws_size) break;
    if (chunkT == 1) return;            // workspace insufficient; fail visibly
    chunkT = 1;
  }

  auto cdiv = [](int a, int b) { return (a + b - 1) / b; };

  init_k<<<NT, 256, 0, stream>>>(hbuf, (unsigned int*)hb0);

  // rank-480 precompute (exact f32)
  sgemm_k<<<cdiv(R * 512, 256), 256, 0, stream>>>(r_emb, Wm1, bm1, nullptr, 1.f, hidden, R, 512, H, 0);
  sgemm_k<<<cdiv(R * H, 256), 256, 0, stream>>>(hidden, Wm2, bm2, nullptr, 1.f, mapped, R, H, 512, 0);
  sgemm_k<<<cdiv(R * H, 256), 256, 0, stream>>>(mapped, Wattn, battn, nullptr, 1.f, t1, R, H, H, 0);
  sgemm_k<<<cdiv(R * R, 256), 256, 0, stream>>>(t1, mapped, nullptr, nullptr, 1.f, B480, R, R, H, 1);
  sgemm_k<<<cdiv(R * 768, 256), 256, 0, stream>>>(mapped, Wih, nullptr, nullptr, 1.f, MW, R, 768, H, 0);
  sgemm_k<<<cdiv(R * H, 256), 256, 0, stream>>>(mapped, Wh1, bh1, nullptr, 1.f, p1, R, H, H, 0);
  sgemm_k<<<cdiv(R * H, 256), 256, 0, stream>>>(p1, Wh2, bh2, mapped, 0.1f, P, R, H, H, 0);
  sgemm_k<<<cdiv(R * 768, 256), 256, 0, stream>>>(P, Whh, bhh, nullptr, 1.f, PW, R, 768, H, 0);
  g2_k<<<cdiv(R * H, 256), 256, 0, stream>>>(MW, PW, P, bih, G2);
  transpose_w_k<<<cdiv(R * 768, 256), 256, 0, stream>>>(MW, MWT, R, 768);
  transpose_w_k<<<cdiv(H * 768, 256), 256, 0, stream>>>(Whh, WhhT, H, 768);
  transpose_w_k<<<cdiv(H * H, 256), 256, 0, stream>>>(Walign, WalignT, H, H);
  bsum_k<<<3, 256, 0, stream>>>(bih, bhh, bsum);

  // scan: batched softmax + batched gi GEMM, then fused gh+gates per step
  u16* hcur = hb0;
  u16* hnxt = hb1;
  for (int t0 = 0; t0 < TT; t0 += chunkT) {
    softmax_all_k<<<chunkT * (NT / 4), 256, 0, stream>>>(part_e, B480, rel_idx, attn_all, t0);
    gemm_k<0><<<dim3(6, chunkT * (NT / 128)), 256, 0, stream>>>(
        attn_all, MWT, bsum, nullptr, gi_all, chunkT * NT, 768, R, nullptr, nullptr);
    for (int tt = 0; tt < chunkT; ++tt) {
      ghgates_k<<<dim3(4, NT / 128), 256, 0, stream>>>(
          hcur, WhhT, bhh, gi_all + (size_t)tt * NT * 768, hbuf, hnxt);
      u16* tmp = hcur; hcur = hnxt; hnxt = tmp;
    }
  }

  // aligned sub + lhs + match partials
  gather_sub_k<<<NT / 4, 256, 0, stream>>>(pre_emb, sub_idx, sub_b);
  gemm_k<0><<<dim3(2, 64), 256, 0, stream>>>(sub_b, WalignT, balign, asub, nullptr, NT, H, H, nullptr, nullptr);
  lhsmatch_k<<<512, 256, 0, stream>>>(rel_idx, P, G2, hbuf, asub, lhs_b, mpart);

  // aligned entity table (bf16, [NE][H] = Bt layout for final GEMM)
  cvt_pre_k<<<NE / 4, 256, 0, stream>>>(pre_emb, pre_b);
  gemm_k<0><<<dim3(2, 180), 256, 0, stream>>>(pre_b, WalignT, balign, nullptr, alT, NE, H, H, nullptr, nullptr);

  // final score GEMM with sigmoid + softplus epilogue
  gemm_k<1><<<dim3(180, 64), 256, 0, stream>>>(lhs_b, alT, nullptr, nullptr, nullptr, NT, NE, H, out + 2, spart);

  // pos + final scalars
  pos_k<<<2048, 256, 0, stream>>>(lhs_b, alT, obj_idx, posar);
  finalize_k<<<1, 256, 0, stream>>>(mpart, spart, posar, out);
}

// Round 4
// 1133.610 us; speedup vs baseline: 1.8890x; 1.6051x over previous
//
#include <hip/hip_runtime.h>
#include <hip/hip_bf16.h>
#include <stdint.h>

#define DEV __device__ __forceinline__

typedef unsigned short u16;
typedef __attribute__((ext_vector_type(8))) short bf16x8;
typedef __attribute__((ext_vector_type(4))) float f32x4;
typedef __attribute__((ext_vector_type(4))) unsigned short u16x4;

constexpr int H  = 256;
constexpr int R  = 480;
constexpr int NE = 23000;
constexpr int NT = 8192;
constexpr int TT = 10;

DEV u16 f2b(float f) {
  union { float f; unsigned u; } x; x.f = f;
  unsigned u = x.u;
  return (u16)((u + 0x7fffu + ((u >> 16) & 1u)) >> 16);
}
DEV float b2f(u16 h) {
  union { unsigned u; float f; } x; x.u = ((unsigned)h) << 16;
  return x.f;
}

DEV void gload_lds16(const u16* g, u16* lds) {
  __builtin_amdgcn_global_load_lds(
      (const __attribute__((address_space(1))) unsigned int*)g,
      (__attribute__((address_space(3))) unsigned int*)lds, 16, 0, 0);
}

// ---------------- init: zero h (f32) and h_b0 (bf16) ----------------
__global__ void init_k(float* __restrict__ h, unsigned int* __restrict__ hb) {
  const int idx = blockIdx.x * 256 + threadIdx.x;   // NT*H threads
  h[idx] = 0.f;
  if (idx < (NT * H) / 2) hb[idx] = 0u;
}

// ---------------- fused rank-480 precompute (row-local chain) --------------
// Per block r: hidden -> mapped -> {t1, MW/MWT, p1 -> P -> PW -> G2}
__launch_bounds__(256)
__global__ void stageA_k(const float* __restrict__ r_emb,
                         const float* __restrict__ Wm1, const float* __restrict__ bm1,
                         const float* __restrict__ Wm2, const float* __restrict__ bm2,
                         const float* __restrict__ Wattn, const float* __restrict__ battn,
                         const float* __restrict__ Wih,
                         const float* __restrict__ Wh1, const float* __restrict__ bh1,
                         const float* __restrict__ Wh2, const float* __restrict__ bh2,
                         const float* __restrict__ Whh, const float* __restrict__ bhh,
                         const float* __restrict__ bih,
                         float* __restrict__ mapped, float* __restrict__ t1,
                         float* __restrict__ Pg, float* __restrict__ G2,
                         u16* __restrict__ MWT) {
  __shared__ float re[256], hid[512], mp[256], p1l[256], Pl[256];
  const int r = blockIdx.x, j = threadIdx.x;
  re[j] = r_emb[(size_t)r * 256 + j];
  __syncthreads();
  float s0 = bm1[j], s1 = bm1[j + 256];
  for (int k = 0; k < 256; ++k) {
    const float a = re[k];
    s0 += a * Wm1[(size_t)k * 512 + j];
    s1 += a * Wm1[(size_t)k * 512 + j + 256];
  }
  hid[j] = s0; hid[j + 256] = s1;
  __syncthreads();
  float m = bm2[j];
  for (int k = 0; k < 512; ++k) m += hid[k] * Wm2[(size_t)k * 256 + j];
  mp[j] = m; mapped[(size_t)r * 256 + j] = m;
  __syncthreads();
  // t1 = mapped @ Wattn + battn
  float tv = battn[j];
  for (int k = 0; k < 256; ++k) tv += mp[k] * Wattn[(size_t)k * 256 + j];
  t1[(size_t)r * 256 + j] = tv;
  // MW = mapped @ Wih (raw, no bias) -> MWT (bf16, transposed) + regs
  float mw0 = 0.f, mw1 = 0.f, mw2 = 0.f;
  for (int k = 0; k < 256; ++k) {
    const float a = mp[k];
    mw0 += a * Wih[(size_t)k * 768 + j];
    mw1 += a * Wih[(size_t)k * 768 + j + 256];
    mw2 += a * Wih[(size_t)k * 768 + j + 512];
  }
  MWT[(size_t)j * 480 + r] = f2b(mw0);
  MWT[(size_t)(j + 256) * 480 + r] = f2b(mw1);
  MWT[(size_t)(j + 512) * 480 + r] = f2b(mw2);
  // p1 -> P = 0.1*(p1@Wh2+bh2) + mapped
  float pv = bh1[j];
  for (int k = 0; k < 256; ++k) pv += mp[k] * Wh1[(size_t)k * 256 + j];
  p1l[j] = pv;
  __syncthreads();
  float Pv = bh2[j];
  for (int k = 0; k < 256; ++k) Pv += p1l[k] * Wh2[(size_t)k * 256 + j];
  Pv = 0.1f * Pv + mp[j];
  Pl[j] = Pv; Pg[(size_t)r * 256 + j] = Pv;
  __syncthreads();
  // PW = P @ Whh + bhh ; G2 = gru(x=mapped, h=P)
  float pw0 = bhh[j], pw1 = bhh[j + 256], pw2 = bhh[j + 512];
  for (int k = 0; k < 256; ++k) {
    const float a = Pl[k];
    pw0 += a * Whh[(size_t)k * 768 + j];
    pw1 += a * Whh[(size_t)k * 768 + j + 256];
    pw2 += a * Whh[(size_t)k * 768 + j + 512];
  }
  const float rg = 1.f / (1.f + __expf(-(mw0 + bih[j] + pw0)));
  const float zg = 1.f / (1.f + __expf(-(mw1 + bih[j + 256] + pw1)));
  const float ng = tanhf(mw2 + bih[j + 512] + rg * pw2);
  G2[(size_t)r * 256 + j] = (1.f - zg) * ng + zg * Pv;
}

// ---------------- B480 = t1 @ mapped^T (exact f32) -------------------------
__global__ void sgemm_bt_k(const float* __restrict__ A, const float* __restrict__ W,
                           float* __restrict__ C, int M, int N, int K) {
  const int idx = blockIdx.x * 256 + threadIdx.x;
  if (idx >= M * N) return;
  const int i = idx / N, j = idx % N;
  float s = 0.f;
  const float* a = A + (size_t)i * K;
  const float* w = W + (size_t)j * K;
  for (int k = 0; k < K; ++k) s += a[k] * w[k];
  C[idx] = s;
}

// ---------------- weight transposes + combined bias ------------------------
__global__ void prep_k(const float* __restrict__ Whh, const float* __restrict__ Walign,
                       const float* __restrict__ bih, const float* __restrict__ bhh,
                       u16* __restrict__ WhhT, u16* __restrict__ WalignT,
                       float* __restrict__ bsum) {
  const int b = blockIdx.x, tid = threadIdx.x;
  if (b < 768) {
    WhhT[(size_t)b * 256 + tid] = f2b(Whh[(size_t)tid * 768 + b]);
  } else if (b < 1024) {
    const int n = b - 768;
    WalignT[(size_t)n * 256 + tid] = f2b(Walign[(size_t)tid * 256 + n]);
  } else {
    const int c = (b - 1024) * 256 + tid;
    if (c < 768) bsum[c] = bih[c] + (c < 512 ? bhh[c] : 0.f);
  }
}

// ---------------- masked softmax for all steps -----------------------------
__global__ void softmax_all_k(const float* __restrict__ part, const float* __restrict__ B480,
                              const int* __restrict__ rel_idx, u16* __restrict__ attn,
                              int t0) {
  const int task = blockIdx.x * 4 + (threadIdx.x >> 6);
  const int lane = threadIdx.x & 63;
  const int tt = task >> 13;            // /NT
  const int i  = task & (NT - 1);
  const float* cur = part + (size_t)i * (TT * R) + (size_t)(t0 + tt) * R;
  const float* b = B480 + (size_t)rel_idx[i] * R;
  float v[8];
  float m = -3e38f;
  #pragma unroll
  for (int j = 0; j < 8; ++j) {
    const int r = lane + j * 64;
    float val = -1e9f;
    if (r < R) {
      const float c = cur[r];
      val = (c == 0.f) ? -1e9f : c * b[r];
      m = fmaxf(m, val);
    }
    v[j] = val;
  }
  #pragma unroll
  for (int o = 32; o; o >>= 1) m = fmaxf(m, __shfl_xor(m, o));
  float s = 0.f;
  #pragma unroll
  for (int j = 0; j < 8; ++j) {
    const int r = lane + j * 64;
    if (r < R) { v[j] = __expf(v[j] - m); s += v[j]; }
  }
  #pragma unroll
  for (int o = 32; o; o >>= 1) s += __shfl_xor(s, o);
  const float inv = 1.f / s;
  u16* arow = attn + (size_t)task * R;
  #pragma unroll
  for (int j = 0; j < 8; ++j) {
    const int r = lane + j * 64;
    if (r < R) arow[r] = f2b(v[j] * inv);
  }
}

// ---------------- fused gh GEMM + GRU gates (64-row tiles, T14 prefetch) ---
__launch_bounds__(256)
__global__ void ghgates_k(const u16* __restrict__ hb, const u16* __restrict__ WhhT,
                          const float* __restrict__ bhh, const u16* __restrict__ gi,
                          float* __restrict__ h, u16* __restrict__ hb_out) {
  __shared__ __align__(16) u16 As[64 * 32];
  __shared__ __align__(16) u16 Bs[192 * 32];
  const int tid = threadIdx.x;
  const int lane = tid & 63;
  const int wv = tid >> 6;
  const int cg = blockIdx.x;            // 0..3
  const int m0 = blockIdx.y * 64;
  const int wr0 = wv * 16;
  const int fr = lane & 15;
  const int fq = lane >> 4;

  // T14: prefetch epilogue operands (gi triplet + h) before the GEMM
  const int row_e = m0 + wr0 + fr;
  u16x4 g_r[4], g_z[4], g_n[4];
  f32x4 hv[4], bn;
  #pragma unroll
  for (int nc = 0; nc < 4; ++nc) {
    const int c = cg * 64 + nc * 16 + fq * 4;
    const size_t gb = (size_t)row_e * 768 + c;
    g_r[nc] = *(const u16x4*)&gi[gb];
    g_z[nc] = *(const u16x4*)&gi[gb + 256];
    g_n[nc] = *(const u16x4*)&gi[gb + 512];
    hv[nc] = *(const f32x4*)&h[(size_t)row_e * H + c];
  }
  {
    const int c = cg * 64 + fq * 4;
    bn = *(const f32x4*)&bhh[512 + c];   // nc-invariant? no: add nc*16 below
  }

  f32x4 acc[12] = {};
  for (int k0 = 0; k0 < H; k0 += 32) {
    __syncthreads();
    {                                    // A: 64 rows x 32 K = 256 chunks
      const int row = tid >> 2, cc = tid & 3;
      gload_lds16(hb + (size_t)(m0 + row) * H + k0 + cc * 8,
                  &As[(wv * 64) * 8]);
    }
    #pragma unroll
    for (int it = 0; it < 3; ++it) {     // B: 192 vrows x 32 K
      const int c = it * 256 + tid;
      const int vrow = c >> 2, cc = c & 3;
      const int col = (vrow >> 6) * 256 + cg * 64 + (vrow & 63);
      gload_lds16(WhhT + (size_t)col * H + k0 + cc * 8,
                  &Bs[(it * 256 + wv * 64) * 8]);
    }
    __syncthreads();
    const bf16x8 a = *(const bf16x8*)&As[(wr0 + fr) * 32 + fq * 8];
    bf16x8 b[12];
    #pragma unroll
    for (int ni = 0; ni < 12; ++ni)
      b[ni] = *(const bf16x8*)&Bs[(ni * 16 + fr) * 32 + fq * 8];
    #pragma unroll
    for (int ni = 0; ni < 12; ++ni)
      acc[ni] = __builtin_amdgcn_mfma_f32_16x16x32_bf16(b[ni], a, acc[ni], 0, 0, 0);
  }

  #pragma unroll
  for (int nc = 0; nc < 4; ++nc) {
    const int c = cg * 64 + nc * 16 + fq * 4;
    const f32x4 bnn = *(const f32x4*)&bhh[512 + c];
    const size_t hi = (size_t)row_e * H + c;
    f32x4 hn;
    u16x4 hb4;
    #pragma unroll
    for (int j = 0; j < 4; ++j) {
      const float rg = 1.f / (1.f + __expf(-(b2f(g_r[nc][j]) + acc[nc][j])));
      const float zg = 1.f / (1.f + __expf(-(b2f(g_z[nc][j]) + acc[4 + nc][j])));
      const float ng = tanhf(b2f(g_n[nc][j]) + rg * (acc[8 + nc][j] + bnn[j]));
      hn[j] = (1.f - zg) * ng + zg * hv[nc][j];
      hb4[j] = f2b(hn[j]);
    }
    *(f32x4*)&h[hi] = hn;
    *(u16x4*)&hb_out[hi] = hb4;
  }
}

// ---------------- gathers / converts (vectorized) --------------------------
__global__ void gather_sub_k(const float* __restrict__ pre, const int* __restrict__ sub,
                             u16* __restrict__ sb) {
  const int q = blockIdx.x * 256 + threadIdx.x;   // NT*H/4
  const int i = q >> 6, c = (q & 63) * 4;
  const f32x4 v = *(const f32x4*)&pre[(size_t)sub[i] * H + c];
  u16x4 o;
  #pragma unroll
  for (int j = 0; j < 4; ++j) o[j] = f2b(v[j]);
  *(u16x4*)&sb[(size_t)q * 4] = o;
}
__global__ void cvt_pre_k(const float* __restrict__ pre, u16* __restrict__ pb) {
  const int q = blockIdx.x * 256 + threadIdx.x;   // NE*H/4
  const f32x4 v = *(const f32x4*)&pre[(size_t)q * 4];
  u16x4 o;
  #pragma unroll
  for (int j = 0; j < 4; ++j) o[j] = f2b(v[j]);
  *(u16x4*)&pb[(size_t)q * 4] = o;
}

// ---------------- pos_i = dot(lhs[i], alignedT[obj[i]]) --------------------
__global__ void pos_k(const u16* __restrict__ lhs, const u16* __restrict__ alT,
                      const int* __restrict__ obj, float* __restrict__ pos) {
  const int row = blockIdx.x * 4 + (threadIdx.x >> 6);
  const int lane = threadIdx.x & 63;
  const u16x4 av = *(const u16x4*)&lhs[(size_t)row * H + lane * 4];
  const u16x4 bv = *(const u16x4*)&alT[(size_t)obj[row] * H + lane * 4];
  float s = 0.f;
  #pragma unroll
  for (int j = 0; j < 4; ++j) s += b2f(av[j]) * b2f(bv[j]);
  #pragma unroll
  for (int o = 32; o; o >>= 1) s += __shfl_down(s, o);
  if (lane == 0) pos[row] = s;
}

// ---------------- final scalar reduction -----------------------------------
__global__ void finalize_k(const float* __restrict__ mp, const float* __restrict__ sp,
                           const float* __restrict__ pos, float* __restrict__ out) {
  const int tid = threadIdx.x;
  float s1 = 0.f, s2 = 0.f, s3 = 0.f;
  for (int i = tid; i < 128; i += 256) s1 += mp[i];
  for (int i = tid; i < 11520; i += 256) s2 += sp[i];
  for (int i = tid; i < 8192; i += 256) s3 += pos[i];
  #pragma unroll
  for (int o = 32; o; o >>= 1) {
    s1 += __shfl_down(s1, o); s2 += __shfl_down(s2, o); s3 += __shfl_down(s3, o);
  }
  __shared__ float r1[4], r2[4], r3[4];
  if ((tid & 63) == 0) { r1[tid >> 6] = s1; r2[tid >> 6] = s2; r3[tid >> 6] = s3; }
  __syncthreads();
  if (tid == 0) {
    const float a = r1[0] + r1[1] + r1[2] + r1[3];
    const float b = r2[0] + r2[1] + r2[2] + r2[3];
    const float c = r3[0] + r3[1] + r3[2] + r3[3];
    out[0] = a / 2097152.f;               // mean over 8192*256
    out[1] = (b - c) / 188416000.f;       // (softplus sum - pos sum)/(8192*23000)
  }
}

// ---------------- bf16 MFMA GEMM: C[M,N] = A[M,K] @ Bt[N,K]^T --------------
// MODE 0: C = A@B + bias -> Cf/Cb
// MODE 1: sigmoid -> out2, softplus partials -> part
// MODE 2: asub epilogue: lhs = (v+balign)*G2[rel], match partials -> part
template <int MODE>
__launch_bounds__(256)
__global__ void gemm_k(const u16* __restrict__ A, const u16* __restrict__ Bt,
                       const float* __restrict__ bias,
                       float* __restrict__ Cf, u16* __restrict__ Cb,
                       int M, int N, int K,
                       float* __restrict__ out2, float* __restrict__ part,
                       const int* __restrict__ rel_idx, const float* __restrict__ Pf,
                       const float* __restrict__ G2f, const float* __restrict__ hf) {
  __shared__ __align__(16) u16 As[128 * 32];
  __shared__ __align__(16) u16 Bs[128 * 32];
  __shared__ float red[4];
  const int tid = threadIdx.x;
  const int lane = tid & 63;
  const int wv = tid >> 6;
  const int nbx = gridDim.x;
  int flat = blockIdx.y * nbx + blockIdx.x;
  const int nwg = nbx * gridDim.y;
  if ((nwg & 7) == 0) flat = (flat & 7) * (nwg >> 3) + (flat >> 3);
  const int bx = flat % nbx;
  const int by = flat / nbx;
  const int m0 = by * 128;
  const int n0 = bx * 128;
  const int wm = (wv >> 1) * 64;
  const int wn = (wv & 1) * 64;
  const int fr = lane & 15;
  const int fq = lane >> 4;
  f32x4 acc[4][4] = {};

  for (int k0 = 0; k0 < K; k0 += 32) {
    __syncthreads();
    #pragma unroll
    for (int it = 0; it < 2; ++it) {
      const int c = it * 256 + tid;       // 16B chunk id, 512 per tile
      const int row = c >> 2;
      const int cc = c & 3;
      int gr = m0 + row; gr = gr < M ? gr : M - 1;
      gload_lds16(A + (size_t)gr * K + k0 + cc * 8, &As[(it * 256 + wv * 64) * 8]);
      int nr = n0 + row; nr = nr < N ? nr : N - 1;
      gload_lds16(Bt + (size_t)nr * K + k0 + cc * 8, &Bs[(it * 256 + wv * 64) * 8]);
    }
    __syncthreads();
    bf16x8 a[4], b[4];
    #pragma unroll
    for (int mi = 0; mi < 4; ++mi)
      a[mi] = *(const bf16x8*)&As[(wm + mi * 16 + fr) * 32 + fq * 8];
    #pragma unroll
    for (int ni = 0; ni < 4; ++ni)
      b[ni] = *(const bf16x8*)&Bs[(wn + ni * 16 + fr) * 32 + fq * 8];
    #pragma unroll
    for (int mi = 0; mi < 4; ++mi)
      #pragma unroll
      for (int ni = 0; ni < 4; ++ni)
        acc[mi][ni] = __builtin_amdgcn_mfma_f32_16x16x32_bf16(b[ni], a[mi], acc[mi][ni], 0, 0, 0);
  }

  float local = 0.f;
  #pragma unroll
  for (int mi = 0; mi < 4; ++mi) {
    const int rowm = m0 + wm + mi * 16 + fr;
    int rel = 0;
    if (MODE == 2) rel = rel_idx[rowm];
    #pragma unroll
    for (int ni = 0; ni < 4; ++ni) {
      const int col = n0 + wn + ni * 16 + fq * 4;   // quad base, col%4==0
      if (rowm < M && col < N) {
        f32x4 v = acc[mi][ni];
        if (MODE == 0) {
          if (bias != nullptr) {
            const f32x4 bv = *(const f32x4*)&bias[col];
            #pragma unroll
            for (int j = 0; j < 4; ++j) v[j] += bv[j];
          }
          if (Cf) *(f32x4*)&Cf[(size_t)rowm * N + col] = v;
          if (Cb) {
            u16x4 o;
            #pragma unroll
            for (int j = 0; j < 4; ++j) o[j] = f2b(v[j]);
            *(u16x4*)&Cb[(size_t)rowm * N + col] = o;
          }
        } else if (MODE == 1) {
          f32x4 sg;
          #pragma unroll
          for (int j = 0; j < 4; ++j) {
            const float s = v[j];
            const float sig = 1.f / (1.f + __expf(-s));
            sg[j] = sig;
            const float om = 1.f - sig;
            local += (om > 0.f) ? -__logf(om) : s;
          }
          *(f32x4*)&out2[(size_t)rowm * N + col] = sg;
        } else {
          const f32x4 bv = *(const f32x4*)&bias[col];
          const f32x4 Pv = *(const f32x4*)&Pf[(size_t)rel * H + col];
          const f32x4 Gv = *(const f32x4*)&G2f[(size_t)rel * H + col];
          const f32x4 hv = *(const f32x4*)&hf[(size_t)rowm * H + col];
          u16x4 o;
          #pragma unroll
          for (int j = 0; j < 4; ++j) {
            const float d = Pv[j] - hv[j];
            local += d * d;
            o[j] = f2b((v[j] + bv[j]) * Gv[j]);
          }
          *(u16x4*)&Cb[(size_t)rowm * N + col] = o;
        }
      }
    }
  }
  if (MODE != 0) {
    #pragma unroll
    for (int o = 32; o; o >>= 1) local += __shfl_down(local, o);
    if (lane == 0) red[wv] = local;
    __syncthreads();
    if (tid == 0) part[blockIdx.y * gridDim.x + blockIdx.x] = red[0] + red[1] + red[2] + red[3];
  }
}

extern "C" void kernel_launch(void* const* d_in, const int* in_sizes, int n_in,
                              void* d_out, int out_size, void* d_ws, size_t ws_size,
                              hipStream_t stream) {
  const float* pre_emb = (const float*)d_in[0];
  const float* r_emb   = (const float*)d_in[1];
  const float* part_e  = (const float*)d_in[2];
  const int*   sub_idx = (const int*)d_in[3];
  const int*   rel_idx = (const int*)d_in[4];
  const int*   obj_idx = (const int*)d_in[5];
  const float* Wm1 = (const float*)d_in[7];  const float* bm1 = (const float*)d_in[8];
  const float* Wm2 = (const float*)d_in[9];  const float* bm2 = (const float*)d_in[10];
  const float* Wattn = (const float*)d_in[11]; const float* battn = (const float*)d_in[12];
  const float* Wh1 = (const float*)d_in[13]; const float* bh1 = (const float*)d_in[14];
  const float* Wh2 = (const float*)d_in[15]; const float* bh2 = (const float*)d_in[16];
  const float* Walign = (const float*)d_in[17]; const float* balign = (const float*)d_in[18];
  const float* Wih = (const float*)d_in[19]; const float* Whh = (const float*)d_in[20];
  const float* bih = (const float*)d_in[21]; const float* bhh = (const float*)d_in[22];
  float* out = (float*)d_out;

  char* w = (char*)d_ws;
  size_t off = 0;
  auto alloc = [&](size_t bytes) -> void* {
    off = (off + 255) & ~(size_t)255;
    void* p = w + off;
    off += bytes;
    return p;
  };
  float* mapped = (float*)alloc((size_t)R * H * 4);
  float* t1     = (float*)alloc((size_t)R * H * 4);
  float* B480   = (float*)alloc((size_t)R * R * 4);
  float* P      = (float*)alloc((size_t)R * H * 4);
  float* G2     = (float*)alloc((size_t)R * H * 4);
  u16* MWT      = (u16*)alloc((size_t)768 * R * 2);
  u16* WhhT     = (u16*)alloc((size_t)768 * H * 2);
  u16* WalignT  = (u16*)alloc((size_t)H * H * 2);
  float* bsum   = (float*)alloc(768 * 4);
  float* hbuf   = (float*)alloc((size_t)NT * H * 4);
  u16* hb0      = (u16*)alloc((size_t)NT * H * 2);
  u16* hb1      = (u16*)alloc((size_t)NT * H * 2);
  u16* lhs_b    = (u16*)alloc((size_t)NT * H * 2);
  u16* sub_b    = (u16*)alloc((size_t)NT * H * 2);
  u16* pre_b    = (u16*)alloc((size_t)NE * H * 2);
  u16* alT      = (u16*)alloc((size_t)NE * H * 2);
  float* mpart  = (float*)alloc(128 * 4);
  float* spart  = (float*)alloc(11520 * 4);
  float* posar  = (float*)alloc(8192 * 4);
  const size_t fixed_end = off;

  // chunked scan buffers: try all 10 steps at once, fall back to 1
  int chunkT = TT;
  u16 *attn_all = nullptr, *gi_all = nullptr;
  for (;;) {
    off = fixed_end;
    attn_all = (u16*)alloc((size_t)chunkT * NT * R * 2);
    gi_all   = (u16*)alloc((size_t)chunkT * NT * 768 * 2);
    if (off <= ws_size) break;
    if (chunkT == 1) return;            // workspace insufficient; fail visibly
    chunkT = 1;
  }

  init_k<<<NT, 256, 0, stream>>>(hbuf, (unsigned int*)hb0);

  // fused rank-480 precompute
  stageA_k<<<R, 256, 0, stream>>>(r_emb, Wm1, bm1, Wm2, bm2, Wattn, battn, Wih,
                                  Wh1, bh1, Wh2, bh2, Whh, bhh, bih,
                                  mapped, t1, P, G2, MWT);
  sgemm_bt_k<<<(R * R + 255) / 256, 256, 0, stream>>>(t1, mapped, B480, R, R, H);
  prep_k<<<1027, 256, 0, stream>>>(Whh, Walign, bih, bhh, WhhT, WalignT, bsum);

  // scan: batched softmax + batched gi GEMM, then fused gh+gates per step
  u16* hcur = hb0;
  u16* hnxt = hb1;
  for (int t0 = 0; t0 < TT; t0 += chunkT) {
    softmax_all_k<<<chunkT * (NT / 4), 256, 0, stream>>>(part_e, B480, rel_idx, attn_all, t0);
    gemm_k<0><<<dim3(6, chunkT * (NT / 128)), 256, 0, stream>>>(
        attn_all, MWT, bsum, nullptr, gi_all, chunkT * NT, 768, R,
        nullptr, nullptr, nullptr, nullptr, nullptr, nullptr);
    for (int tt = 0; tt < chunkT; ++tt) {
      ghgates_k<<<dim3(4, NT / 64), 256, 0, stream>>>(
          hcur, WhhT, bhh, gi_all + (size_t)tt * NT * 768, hbuf, hnxt);
      u16* tmp = hcur; hcur = hnxt; hnxt = tmp;
    }
  }

  // sub gather + fused (asub GEMM + lhs + match partials)
  gather_sub_k<<<NT / 4, 256, 0, stream>>>(pre_emb, sub_idx, sub_b);
  gemm_k<2><<<dim3(2, 64), 256, 0, stream>>>(
      sub_b, WalignT, balign, nullptr, lhs_b, NT, H, H,
      nullptr, mpart, rel_idx, P, G2, hbuf);

  // aligned entity table (bf16, [NE][H] = Bt layout for final GEMM)
  cvt_pre_k<<<NE / 4, 256, 0, stream>>>(pre_emb, pre_b);
  gemm_k<0><<<dim3(2, 180), 256, 0, stream>>>(
      pre_b, WalignT, balign, nullptr, alT, NE, H, H,
      nullptr, nullptr, nullptr, nullptr, nullptr, nullptr);

  // final score GEMM with sigmoid + softplus epilogue
  gemm_k<1><<<dim3(180, 64), 256, 0, stream>>>(
      lhs_b, alT, nullptr, nullptr, nullptr, NT, NE, H,
      out + 2, spart, nullptr, nullptr, nullptr, nullptr);

  // pos + final scalars
  pos_k<<<2048, 256, 0, stream>>>(lhs_b, alT, obj_idx, posar);
  finalize_k<<<1, 256, 0, stream>>>(mpart, spart, posar, out);
}

// Round 5
// 1109.196 us; speedup vs baseline: 1.9306x; 1.0220x over previous
//
#include <hip/hip_runtime.h>
#include <hip/hip_bf16.h>
#include <stdint.h>

#define DEV __device__ __forceinline__

typedef unsigned short u16;
typedef __attribute__((ext_vector_type(8))) short bf16x8;
typedef __attribute__((ext_vector_type(4))) float f32x4;
typedef __attribute__((ext_vector_type(4))) unsigned short u16x4;

constexpr int H  = 256;
constexpr int R  = 480;
constexpr int RP = 512;   // padded K for the gi GEMM
constexpr int NE = 23000;
constexpr int NT = 8192;
constexpr int TT = 10;

DEV u16 f2b(float f) {
  union { float f; unsigned u; } x; x.f = f;
  unsigned u = x.u;
  return (u16)((u + 0x7fffu + ((u >> 16) & 1u)) >> 16);
}
DEV float b2f(u16 h) {
  union { unsigned u; float f; } x; x.u = ((unsigned)h) << 16;
  return x.f;
}

DEV void gload_lds16(const u16* g, u16* lds) {
  __builtin_amdgcn_global_load_lds(
      (const __attribute__((address_space(1))) unsigned int*)g,
      (__attribute__((address_space(3))) unsigned int*)lds, 16, 0, 0);
}

// ---------------- fused rank-480 precompute (row-local chain) --------------
__launch_bounds__(256)
__global__ void stageA_k(const float* __restrict__ r_emb,
                         const float* __restrict__ Wm1, const float* __restrict__ bm1,
                         const float* __restrict__ Wm2, const float* __restrict__ bm2,
                         const float* __restrict__ Wattn, const float* __restrict__ battn,
                         const float* __restrict__ Wih,
                         const float* __restrict__ Wh1, const float* __restrict__ bh1,
                         const float* __restrict__ Wh2, const float* __restrict__ bh2,
                         const float* __restrict__ Whh, const float* __restrict__ bhh,
                         const float* __restrict__ bih,
                         float* __restrict__ mapped, float* __restrict__ t1,
                         float* __restrict__ Pg, float* __restrict__ G2,
                         u16* __restrict__ MWT) {
  __shared__ float re[256], hid[512], mp[256], p1l[256], Pl[256];
  const int r = blockIdx.x, j = threadIdx.x;
  re[j] = r_emb[(size_t)r * 256 + j];
  __syncthreads();
  float s0 = bm1[j], s1 = bm1[j + 256];
  for (int k = 0; k < 256; ++k) {
    const float a = re[k];
    s0 += a * Wm1[(size_t)k * 512 + j];
    s1 += a * Wm1[(size_t)k * 512 + j + 256];
  }
  hid[j] = s0; hid[j + 256] = s1;
  __syncthreads();
  float m = bm2[j];
  for (int k = 0; k < 512; ++k) m += hid[k] * Wm2[(size_t)k * 256 + j];
  mp[j] = m; mapped[(size_t)r * 256 + j] = m;
  __syncthreads();
  float tv = battn[j];
  for (int k = 0; k < 256; ++k) tv += mp[k] * Wattn[(size_t)k * 256 + j];
  t1[(size_t)r * 256 + j] = tv;
  float mw0 = 0.f, mw1 = 0.f, mw2 = 0.f;
  for (int k = 0; k < 256; ++k) {
    const float a = mp[k];
    mw0 += a * Wih[(size_t)k * 768 + j];
    mw1 += a * Wih[(size_t)k * 768 + j + 256];
    mw2 += a * Wih[(size_t)k * 768 + j + 512];
  }
  MWT[(size_t)j * RP + r] = f2b(mw0);
  MWT[(size_t)(j + 256) * RP + r] = f2b(mw1);
  MWT[(size_t)(j + 512) * RP + r] = f2b(mw2);
  float pv = bh1[j];
  for (int k = 0; k < 256; ++k) pv += mp[k] * Wh1[(size_t)k * 256 + j];
  p1l[j] = pv;
  __syncthreads();
  float Pv = bh2[j];
  for (int k = 0; k < 256; ++k) Pv += p1l[k] * Wh2[(size_t)k * 256 + j];
  Pv = 0.1f * Pv + mp[j];
  Pl[j] = Pv; Pg[(size_t)r * 256 + j] = Pv;
  __syncthreads();
  float pw0 = bhh[j], pw1 = bhh[j + 256], pw2 = bhh[j + 512];
  for (int k = 0; k < 256; ++k) {
    const float a = Pl[k];
    pw0 += a * Whh[(size_t)k * 768 + j];
    pw1 += a * Whh[(size_t)k * 768 + j + 256];
    pw2 += a * Whh[(size_t)k * 768 + j + 512];
  }
  const float rg = 1.f / (1.f + __expf(-(mw0 + bih[j] + pw0)));
  const float zg = 1.f / (1.f + __expf(-(mw1 + bih[j + 256] + pw1)));
  const float ng = tanhf(mw2 + bih[j + 512] + rg * pw2);
  G2[(size_t)r * 256 + j] = (1.f - zg) * ng + zg * Pv;
}

// ---------------- B480 = t1 @ mapped^T (exact f32) -------------------------
__global__ void sgemm_bt_k(const float* __restrict__ A, const float* __restrict__ W,
                           float* __restrict__ C, int M, int N, int K) {
  const int idx = blockIdx.x * 256 + threadIdx.x;
  if (idx >= M * N) return;
  const int i = idx / N, j = idx % N;
  float s = 0.f;
  const float* a = A + (size_t)i * K;
  const float* w = W + (size_t)j * K;
  for (int k = 0; k < K; ++k) s += a[k] * w[k];
  C[idx] = s;
}

// ---------------- weight transposes + combined bias ------------------------
__global__ void prep_k(const float* __restrict__ Whh, const float* __restrict__ Walign,
                       const float* __restrict__ bih, const float* __restrict__ bhh,
                       u16* __restrict__ WhhT, u16* __restrict__ WalignT,
                       float* __restrict__ bsum) {
  const int b = blockIdx.x, tid = threadIdx.x;
  if (b < 768) {
    WhhT[(size_t)b * 256 + tid] = f2b(Whh[(size_t)tid * 768 + b]);
  } else if (b < 1024) {
    const int n = b - 768;
    WalignT[(size_t)n * 256 + tid] = f2b(Walign[(size_t)tid * 256 + n]);
  } else {
    const int c = (b - 1024) * 256 + tid;
    if (c < 768) bsum[c] = bih[c] + (c < 512 ? bhh[c] : 0.f);
  }
}

// ---------------- masked softmax for all steps (padded to 512 cols) --------
__global__ void softmax_all_k(const float* __restrict__ part, const float* __restrict__ B480,
                              const int* __restrict__ rel_idx, u16* __restrict__ attn) {
  const int task = blockIdx.x * 4 + (threadIdx.x >> 6);
  const int lane = threadIdx.x & 63;
  const int tt = task >> 13;            // /NT
  const int i  = task & (NT - 1);
  const float* cur = part + (size_t)i * (TT * R) + (size_t)tt * R;
  const float* b = B480 + (size_t)rel_idx[i] * R;
  float v[8];
  float m = -3e38f;
  #pragma unroll
  for (int j = 0; j < 8; ++j) {
    const int r = lane + j * 64;
    float val = -1e9f;
    if (r < R) {
      const float c = cur[r];
      val = (c == 0.f) ? -1e9f : c * b[r];
      m = fmaxf(m, val);
    }
    v[j] = val;
  }
  #pragma unroll
  for (int o = 32; o; o >>= 1) m = fmaxf(m, __shfl_xor(m, o));
  float s = 0.f;
  #pragma unroll
  for (int j = 0; j < 8; ++j) {
    const int r = lane + j * 64;
    if (r < R) { v[j] = __expf(v[j] - m); s += v[j]; }
  }
  #pragma unroll
  for (int o = 32; o; o >>= 1) s += __shfl_xor(s, o);
  const float inv = 1.f / s;
  u16* arow = attn + (size_t)task * RP;
  #pragma unroll
  for (int j = 0; j < 8; ++j) {
    const int r = lane + j * 64;           // covers 0..511 exactly
    arow[r] = (r < R) ? f2b(v[j] * inv) : (u16)0;
  }
}

// ---------------- single-launch 10-step scan -------------------------------
// Block owns 32 h-rows for the whole scan: h in f32 regs, bf16 A in LDS
// (swizzled), WhhT staged double-buffered with counted vmcnt.
__launch_bounds__(256)
__global__ void scan_k(const u16* __restrict__ WhhT, const float* __restrict__ bhh,
                       const u16* __restrict__ gi_all, float* __restrict__ hbuf) {
  __shared__ __align__(16) u16 As[32 * 256];
  __shared__ __align__(16) u16 Bs[2][192 * 64];
  const int tid = threadIdx.x;
  const int lane = tid & 63;
  const int wv = tid >> 6;
  const int rf = wv >> 1;
  const int ch = wv & 1;
  const int fr = lane & 15;
  const int fq = lane >> 4;
  const int row_l = rf * 16 + fr;
  const int grow = blockIdx.x * 32 + row_l;
  const int sw = (fr & 7) * 8;

  auto stageB = [&](int buf, int cg, int k0) {
    #pragma unroll
    for (int it = 0; it < 6; ++it) {
      const int c = it * 256 + tid;
      const int vr = c >> 3, s = c & 7;
      const int vcol = ((vr >> 6) * 256) + cg * 64 + (vr & 63);
      gload_lds16(WhhT + (size_t)vcol * 256 + k0 + ((s ^ (vr & 7)) * 8),
                  &Bs[buf][(it * 256 + wv * 64) * 8]);
    }
  };

  float hreg[4][2][4];
  #pragma unroll
  for (int cg = 0; cg < 4; ++cg)
    #pragma unroll
    for (int nn = 0; nn < 2; ++nn)
      #pragma unroll
      for (int j = 0; j < 4; ++j) hreg[cg][nn][j] = 0.f;

  for (int t = 0; t < TT; ++t) {
    const u16* gi = gi_all + (size_t)t * NT * 768;
    #pragma unroll
    for (int cg = 0; cg < 4; ++cg) {
      f32x4 acc[6] = {};
      u16x4 gv[3][2];
      #pragma unroll
      for (int nn = 0; nn < 2; ++nn) {
        const int c = cg * 64 + ch * 32 + nn * 16 + fq * 4;
        const size_t gb = (size_t)grow * 768 + c;
        gv[0][nn] = *(const u16x4*)&gi[gb];
        gv[1][nn] = *(const u16x4*)&gi[gb + 256];
        gv[2][nn] = *(const u16x4*)&gi[gb + 512];
      }
      if (t > 0) {
        stageB(0, cg, 0);
        #pragma unroll
        for (int ki = 0; ki < 4; ++ki) {
          const int cb = ki & 1;
          if (ki < 3) {
            stageB(cb ^ 1, cg, (ki + 1) * 64);
            asm volatile("s_waitcnt vmcnt(6)" ::: "memory");
          } else {
            asm volatile("s_waitcnt vmcnt(0)" ::: "memory");
          }
          __builtin_amdgcn_sched_barrier(0);
          __builtin_amdgcn_s_barrier();
          #pragma unroll
          for (int kk = 0; kk < 2; ++kk) {
            const int ko = (ki * 64 + kk * 32 + fq * 8) ^ sw;
            const bf16x8 a = *(const bf16x8*)&As[row_l * 256 + ko];
            const int bo = (kk * 32 + fq * 8) ^ sw;
            #pragma unroll
            for (int g = 0; g < 3; ++g)
              #pragma unroll
              for (int nn = 0; nn < 2; ++nn) {
                const int vr = g * 64 + ch * 32 + nn * 16 + fr;
                const bf16x8 b = *(const bf16x8*)&Bs[cb][vr * 64 + bo];
                acc[g * 2 + nn] =
                    __builtin_amdgcn_mfma_f32_16x16x32_bf16(b, a, acc[g * 2 + nn], 0, 0, 0);
              }
          }
          __builtin_amdgcn_s_barrier();
        }
      }
      #pragma unroll
      for (int nn = 0; nn < 2; ++nn) {
        const int c = cg * 64 + ch * 32 + nn * 16 + fq * 4;
        const f32x4 bn = *(const f32x4*)&bhh[512 + c];
        #pragma unroll
        for (int j = 0; j < 4; ++j) {
          const float rg = 1.f / (1.f + __expf(-(b2f(gv[0][nn][j]) + acc[nn][j])));
          const float zg = 1.f / (1.f + __expf(-(b2f(gv[1][nn][j]) + acc[2 + nn][j])));
          const float ng = tanhf(b2f(gv[2][nn][j]) + rg * (acc[4 + nn][j] + bn[j]));
          hreg[cg][nn][j] = (1.f - zg) * ng + zg * hreg[cg][nn][j];
        }
      }
    }
    // write h -> As (bf16, swizzled); hbuf f32 at the last step
    #pragma unroll
    for (int cg = 0; cg < 4; ++cg)
      #pragma unroll
      for (int nn = 0; nn < 2; ++nn) {
        const int c = cg * 64 + ch * 32 + nn * 16 + fq * 4;
        u16x4 o;
        #pragma unroll
        for (int j = 0; j < 4; ++j) o[j] = f2b(hreg[cg][nn][j]);
        *(u16x4*)&As[row_l * 256 + (c ^ sw)] = o;
        if (t == TT - 1) {
          f32x4 hv;
          #pragma unroll
          for (int j = 0; j < 4; ++j) hv[j] = hreg[cg][nn][j];
          *(f32x4*)&hbuf[(size_t)grow * 256 + c] = hv;
        }
      }
    __syncthreads();
  }
}

// ---------------- gathers / converts (vectorized) --------------------------
__global__ void gather_sub_k(const float* __restrict__ pre, const int* __restrict__ sub,
                             u16* __restrict__ sb) {
  const int q = blockIdx.x * 256 + threadIdx.x;
  const int i = q >> 6, c = (q & 63) * 4;
  const f32x4 v = *(const f32x4*)&pre[(size_t)sub[i] * H + c];
  u16x4 o;
  #pragma unroll
  for (int j = 0; j < 4; ++j) o[j] = f2b(v[j]);
  *(u16x4*)&sb[(size_t)q * 4] = o;
}
__global__ void cvt_pre_k(const float* __restrict__ pre, u16* __restrict__ pb) {
  const int q = blockIdx.x * 256 + threadIdx.x;
  const f32x4 v = *(const f32x4*)&pre[(size_t)q * 4];
  u16x4 o;
  #pragma unroll
  for (int j = 0; j < 4; ++j) o[j] = f2b(v[j]);
  *(u16x4*)&pb[(size_t)q * 4] = o;
}

// ---------------- pos_i = dot(lhs[i], alignedT[obj[i]]) --------------------
__global__ void pos_k(const u16* __restrict__ lhs, const u16* __restrict__ alT,
                      const int* __restrict__ obj, float* __restrict__ pos) {
  const int row = blockIdx.x * 4 + (threadIdx.x >> 6);
  const int lane = threadIdx.x & 63;
  const u16x4 av = *(const u16x4*)&lhs[(size_t)row * H + lane * 4];
  const u16x4 bv = *(const u16x4*)&alT[(size_t)obj[row] * H + lane * 4];
  float s = 0.f;
  #pragma unroll
  for (int j = 0; j < 4; ++j) s += b2f(av[j]) * b2f(bv[j]);
  #pragma unroll
  for (int o = 32; o; o >>= 1) s += __shfl_down(s, o);
  if (lane == 0) pos[row] = s;
}

// ---------------- final scalar reduction -----------------------------------
__global__ void finalize_k(const float* __restrict__ mp, const float* __restrict__ sp,
                           const float* __restrict__ pos, float* __restrict__ out) {
  const int tid = threadIdx.x;
  float s1 = 0.f, s2 = 0.f, s3 = 0.f;
  for (int i = tid; i < 128; i += 256) s1 += mp[i];
  for (int i = tid; i < 11520; i += 256) s2 += sp[i];
  for (int i = tid; i < 8192; i += 256) s3 += pos[i];
  #pragma unroll
  for (int o = 32; o; o >>= 1) {
    s1 += __shfl_down(s1, o); s2 += __shfl_down(s2, o); s3 += __shfl_down(s3, o);
  }
  __shared__ float r1[4], r2[4], r3[4];
  if ((tid & 63) == 0) { r1[tid >> 6] = s1; r2[tid >> 6] = s2; r3[tid >> 6] = s3; }
  __syncthreads();
  if (tid == 0) {
    const float a = r1[0] + r1[1] + r1[2] + r1[3];
    const float b = r2[0] + r2[1] + r2[2] + r2[3];
    const float c = r3[0] + r3[1] + r3[2] + r3[3];
    out[0] = a / 2097152.f;
    out[1] = (b - c) / 188416000.f;
  }
}

// ---------------- bf16 MFMA GEMM, BK=64, swizzled LDS ----------------------
// MODE 0: C = A@B + bias -> Cf/Cb ; MODE 1: sigmoid/softplus ; MODE 2: lhs+match
template <int MODE>
__launch_bounds__(256)
__global__ void gemm_k(const u16* __restrict__ A, const u16* __restrict__ Bt,
                       const float* __restrict__ bias,
                       float* __restrict__ Cf, u16* __restrict__ Cb,
                       int M, int N, int K,
                       float* __restrict__ out2, float* __restrict__ part,
                       const int* __restrict__ rel_idx, const float* __restrict__ Pf,
                       const float* __restrict__ G2f, const float* __restrict__ hf) {
  __shared__ __align__(16) u16 As[128 * 64];
  __shared__ __align__(16) u16 Bs[128 * 64];
  __shared__ float red[4];
  const int tid = threadIdx.x;
  const int lane = tid & 63;
  const int wv = tid >> 6;
  const int nbx = gridDim.x;
  int flat = blockIdx.y * nbx + blockIdx.x;
  const int nwg = nbx * gridDim.y;
  if ((nwg & 7) == 0) flat = (flat & 7) * (nwg >> 3) + (flat >> 3);
  const int bx = flat % nbx;
  const int by = flat / nbx;
  const int m0 = by * 128;
  const int n0 = bx * 128;
  const int wm = (wv >> 1) * 64;
  const int wn = (wv & 1) * 64;
  const int fr = lane & 15;
  const int fq = lane >> 4;
  const int sw = (lane & 7) * 8;
  f32x4 acc[4][4] = {};

  for (int k0 = 0; k0 < K; k0 += 64) {
    __syncthreads();
    #pragma unroll
    for (int it = 0; it < 4; ++it) {
      const int c = it * 256 + tid;
      const int row = c >> 3, s = c & 7;
      const int sc = (s ^ (row & 7)) * 8;
      int gr = m0 + row; gr = gr < M ? gr : M - 1;
      gload_lds16(A + (size_t)gr * K + k0 + sc, &As[(it * 256 + wv * 64) * 8]);
      int nr = n0 + row; nr = nr < N ? nr : N - 1;
      gload_lds16(Bt + (size_t)nr * K + k0 + sc, &Bs[(it * 256 + wv * 64) * 8]);
    }
    __syncthreads();
    #pragma unroll
    for (int kk = 0; kk < 2; ++kk) {
      const int ko = (kk * 32 + fq * 8) ^ sw;
      bf16x8 a[4], b[4];
      #pragma unroll
      for (int mi = 0; mi < 4; ++mi)
        a[mi] = *(const bf16x8*)&As[(wm + mi * 16 + fr) * 64 + ko];
      #pragma unroll
      for (int ni = 0; ni < 4; ++ni)
        b[ni] = *(const bf16x8*)&Bs[(wn + ni * 16 + fr) * 64 + ko];
      #pragma unroll
      for (int mi = 0; mi < 4; ++mi)
        #pragma unroll
        for (int ni = 0; ni < 4; ++ni)
          acc[mi][ni] = __builtin_amdgcn_mfma_f32_16x16x32_bf16(b[ni], a[mi], acc[mi][ni], 0, 0, 0);
    }
  }

  float local = 0.f;
  #pragma unroll
  for (int mi = 0; mi < 4; ++mi) {
    const int rowm = m0 + wm + mi * 16 + fr;
    int rel = 0;
    if (MODE == 2) rel = rel_idx[rowm];
    #pragma unroll
    for (int ni = 0; ni < 4; ++ni) {
      const int col = n0 + wn + ni * 16 + fq * 4;
      if (rowm < M && col < N) {
        f32x4 v = acc[mi][ni];
        if (MODE == 0) {
          if (bias != nullptr) {
            const f32x4 bv = *(const f32x4*)&bias[col];
            #pragma unroll
            for (int j = 0; j < 4; ++j) v[j] += bv[j];
          }
          if (Cf) *(f32x4*)&Cf[(size_t)rowm * N + col] = v;
          if (Cb) {
            u16x4 o;
            #pragma unroll
            for (int j = 0; j < 4; ++j) o[j] = f2b(v[j]);
            *(u16x4*)&Cb[(size_t)rowm * N + col] = o;
          }
        } else if (MODE == 1) {
          f32x4 sg;
          #pragma unroll
          for (int j = 0; j < 4; ++j) {
            const float s = v[j];
            const float sig = 1.f / (1.f + __expf(-s));
            sg[j] = sig;
            const float om = 1.f - sig;
            local += (om > 0.f) ? -__logf(om) : s;
          }
          *(f32x4*)&out2[(size_t)rowm * N + col] = sg;
        } else {
          const f32x4 bv = *(const f32x4*)&bias[col];
          const f32x4 Pv = *(const f32x4*)&Pf[(size_t)rel * H + col];
          const f32x4 Gv = *(const f32x4*)&G2f[(size_t)rel * H + col];
          const f32x4 hv = *(const f32x4*)&hf[(size_t)rowm * H + col];
          u16x4 o;
          #pragma unroll
          for (int j = 0; j < 4; ++j) {
            const float d = Pv[j] - hv[j];
            local += d * d;
            o[j] = f2b((v[j] + bv[j]) * Gv[j]);
          }
          *(u16x4*)&Cb[(size_t)rowm * N + col] = o;
        }
      }
    }
  }
  if (MODE != 0) {
    #pragma unroll
    for (int o = 32; o; o >>= 1) local += __shfl_down(local, o);
    if (lane == 0) red[wv] = local;
    __syncthreads();
    if (tid == 0) part[blockIdx.y * gridDim.x + blockIdx.x] = red[0] + red[1] + red[2] + red[3];
  }
}

extern "C" void kernel_launch(void* const* d_in, const int* in_sizes, int n_in,
                              void* d_out, int out_size, void* d_ws, size_t ws_size,
                              hipStream_t stream) {
  const float* pre_emb = (const float*)d_in[0];
  const float* r_emb   = (const float*)d_in[1];
  const float* part_e  = (const float*)d_in[2];
  const int*   sub_idx = (const int*)d_in[3];
  const int*   rel_idx = (const int*)d_in[4];
  const int*   obj_idx = (const int*)d_in[5];
  const float* Wm1 = (const float*)d_in[7];  const float* bm1 = (const float*)d_in[8];
  const float* Wm2 = (const float*)d_in[9];  const float* bm2 = (const float*)d_in[10];
  const float* Wattn = (const float*)d_in[11]; const float* battn = (const float*)d_in[12];
  const float* Wh1 = (const float*)d_in[13]; const float* bh1 = (const float*)d_in[14];
  const float* Wh2 = (const float*)d_in[15]; const float* bh2 = (const float*)d_in[16];
  const float* Walign = (const float*)d_in[17]; const float* balign = (const float*)d_in[18];
  const float* Wih = (const float*)d_in[19]; const float* Whh = (const float*)d_in[20];
  const float* bih = (const float*)d_in[21]; const float* bhh = (const float*)d_in[22];
  float* out = (float*)d_out;

  char* w = (char*)d_ws;
  size_t off = 0;
  auto alloc = [&](size_t bytes) -> void* {
    off = (off + 255) & ~(size_t)255;
    void* p = w + off;
    off += bytes;
    return p;
  };
  float* mapped = (float*)alloc((size_t)R * H * 4);
  float* t1     = (float*)alloc((size_t)R * H * 4);
  float* B480   = (float*)alloc((size_t)R * R * 4);
  float* P      = (float*)alloc((size_t)R * H * 4);
  float* G2     = (float*)alloc((size_t)R * H * 4);
  u16* MWT      = (u16*)alloc((size_t)768 * RP * 2);
  u16* WhhT     = (u16*)alloc((size_t)768 * H * 2);
  u16* WalignT  = (u16*)alloc((size_t)H * H * 2);
  float* bsum   = (float*)alloc(768 * 4);
  float* hbuf   = (float*)alloc((size_t)NT * H * 4);
  u16* lhs_b    = (u16*)alloc((size_t)NT * H * 2);
  u16* sub_b    = (u16*)alloc((size_t)NT * H * 2);
  u16* pre_b    = (u16*)alloc((size_t)NE * H * 2);
  u16* alT      = (u16*)alloc((size_t)NE * H * 2);
  float* mpart  = (float*)alloc(128 * 4);
  float* spart  = (float*)alloc(11520 * 4);
  float* posar  = (float*)alloc(8192 * 4);
  u16* attn_all = (u16*)alloc((size_t)TT * NT * RP * 2);
  u16* gi_all   = (u16*)alloc((size_t)TT * NT * 768 * 2);
  if (off > ws_size) return;  // workspace insufficient; fail visibly

  // rank-480 precompute
  hipMemsetAsync(MWT, 0, (size_t)768 * RP * 2, stream);
  stageA_k<<<R, 256, 0, stream>>>(r_emb, Wm1, bm1, Wm2, bm2, Wattn, battn, Wih,
                                  Wh1, bh1, Wh2, bh2, Whh, bhh, bih,
                                  mapped, t1, P, G2, MWT);
  sgemm_bt_k<<<(R * R + 255) / 256, 256, 0, stream>>>(t1, mapped, B480, R, R, H);
  prep_k<<<1027, 256, 0, stream>>>(Whh, Walign, bih, bhh, WhhT, WalignT, bsum);

  // all-step softmax + batched gi GEMM + single-launch scan
  softmax_all_k<<<TT * (NT / 4), 256, 0, stream>>>(part_e, B480, rel_idx, attn_all);
  gemm_k<0><<<dim3(6, TT * (NT / 128)), 256, 0, stream>>>(
      attn_all, MWT, bsum, nullptr, gi_all, TT * NT, 768, RP,
      nullptr, nullptr, nullptr, nullptr, nullptr, nullptr);
  scan_k<<<NT / 32, 256, 0, stream>>>(WhhT, bhh, gi_all, hbuf);

  // sub gather + fused (asub GEMM + lhs + match partials)
  gather_sub_k<<<NT / 4, 256, 0, stream>>>(pre_emb, sub_idx, sub_b);
  gemm_k<2><<<dim3(2, 64), 256, 0, stream>>>(
      sub_b, WalignT, balign, nullptr, lhs_b, NT, H, H,
      nullptr, mpart, rel_idx, P, G2, hbuf);

  // aligned entity table
  cvt_pre_k<<<NE / 4, 256, 0, stream>>>(pre_emb, pre_b);
  gemm_k<0><<<dim3(2, 180), 256, 0, stream>>>(
      pre_b, WalignT, balign, nullptr, alT, NE, H, H,
      nullptr, nullptr, nullptr, nullptr, nullptr, nullptr);

  // final score GEMM with sigmoid + softplus epilogue
  gemm_k<1><<<dim3(180, 64), 256, 0, stream>>>(
      lhs_b, alT, nullptr, nullptr, nullptr, NT, NE, H,
      out + 2, spart, nullptr, nullptr, nullptr, nullptr);

  // pos + final scalars
  pos_k<<<2048, 256, 0, stream>>>(lhs_b, alT, obj_idx, posar);
  finalize_k<<<1, 256, 0, stream>>>(mpart, spart, posar, out);
}

// Round 6
// 1093.621 us; speedup vs baseline: 1.9581x; 1.0142x over previous
//
#include <hip/hip_runtime.h>
#include <hip/hip_bf16.h>
#include <stdint.h>

#define DEV __device__ __forceinline__

typedef unsigned short u16;
typedef __attribute__((ext_vector_type(8))) short bf16x8;
typedef __attribute__((ext_vector_type(4))) float f32x4;
typedef __attribute__((ext_vector_type(4))) unsigned short u16x4;

constexpr int H  = 256;
constexpr int R  = 480;
constexpr int RP = 512;   // padded K for the gi GEMM
constexpr int NE = 23000;
constexpr int NT = 8192;
constexpr int TT = 10;

DEV u16 f2b(float f) {
  union { float f; unsigned u; } x; x.f = f;
  unsigned u = x.u;
  return (u16)((u + 0x7fffu + ((u >> 16) & 1u)) >> 16);
}
DEV float b2f(u16 h) {
  union { unsigned u; float f; } x; x.u = ((unsigned)h) << 16;
  return x.f;
}

DEV void gload_lds16(const u16* g, u16* lds) {
  __builtin_amdgcn_global_load_lds(
      (const __attribute__((address_space(1))) unsigned int*)g,
      (__attribute__((address_space(3))) unsigned int*)lds, 16, 0, 0);
}

// ---------------- fused rank-480 precompute + weight prep ------------------
// Blocks 0..479: row-local chain. Blocks 480..1506: WhhT/WalignT/bsum prep.
__launch_bounds__(256)
__global__ void stageA_k(const float* __restrict__ r_emb,
                         const float* __restrict__ Wm1, const float* __restrict__ bm1,
                         const float* __restrict__ Wm2, const float* __restrict__ bm2,
                         const float* __restrict__ Wattn, const float* __restrict__ battn,
                         const float* __restrict__ Wih,
                         const float* __restrict__ Wh1, const float* __restrict__ bh1,
                         const float* __restrict__ Wh2, const float* __restrict__ bh2,
                         const float* __restrict__ Whh, const float* __restrict__ bhh,
                         const float* __restrict__ bih, const float* __restrict__ Walign,
                         float* __restrict__ mapped, float* __restrict__ t1,
                         float* __restrict__ Pg, float* __restrict__ G2,
                         u16* __restrict__ MWT, u16* __restrict__ WhhT,
                         u16* __restrict__ WalignT, float* __restrict__ bsum) {
  __shared__ float re[256], hid[512], mp[256], p1l[256], Pl[256];
  const int j = threadIdx.x;
  if (blockIdx.x >= 480) {
    const int b = blockIdx.x - 480;
    if (b < 768) {
      WhhT[(size_t)b * 256 + j] = f2b(Whh[(size_t)j * 768 + b]);
    } else if (b < 1024) {
      const int n = b - 768;
      WalignT[(size_t)n * 256 + j] = f2b(Walign[(size_t)j * 256 + n]);
    } else {
      const int c = (b - 1024) * 256 + j;
      if (c < 768) bsum[c] = bih[c] + (c < 512 ? bhh[c] : 0.f);
    }
    return;
  }
  const int r = blockIdx.x;
  re[j] = r_emb[(size_t)r * 256 + j];
  __syncthreads();
  float s0 = bm1[j], s1 = bm1[j + 256];
  for (int k = 0; k < 256; ++k) {
    const float a = re[k];
    s0 += a * Wm1[(size_t)k * 512 + j];
    s1 += a * Wm1[(size_t)k * 512 + j + 256];
  }
  hid[j] = s0; hid[j + 256] = s1;
  __syncthreads();
  float m = bm2[j];
  for (int k = 0; k < 512; ++k) m += hid[k] * Wm2[(size_t)k * 256 + j];
  mp[j] = m; mapped[(size_t)r * 256 + j] = m;
  __syncthreads();
  float tv = battn[j];
  for (int k = 0; k < 256; ++k) tv += mp[k] * Wattn[(size_t)k * 256 + j];
  t1[(size_t)r * 256 + j] = tv;
  float mw0 = 0.f, mw1 = 0.f, mw2 = 0.f;
  for (int k = 0; k < 256; ++k) {
    const float a = mp[k];
    mw0 += a * Wih[(size_t)k * 768 + j];
    mw1 += a * Wih[(size_t)k * 768 + j + 256];
    mw2 += a * Wih[(size_t)k * 768 + j + 512];
  }
  MWT[(size_t)j * RP + r] = f2b(mw0);
  MWT[(size_t)(j + 256) * RP + r] = f2b(mw1);
  MWT[(size_t)(j + 512) * RP + r] = f2b(mw2);
  float pv = bh1[j];
  for (int k = 0; k < 256; ++k) pv += mp[k] * Wh1[(size_t)k * 256 + j];
  p1l[j] = pv;
  __syncthreads();
  float Pv = bh2[j];
  for (int k = 0; k < 256; ++k) Pv += p1l[k] * Wh2[(size_t)k * 256 + j];
  Pv = 0.1f * Pv + mp[j];
  Pl[j] = Pv; Pg[(size_t)r * 256 + j] = Pv;
  __syncthreads();
  float pw0 = bhh[j], pw1 = bhh[j + 256], pw2 = bhh[j + 512];
  for (int k = 0; k < 256; ++k) {
    const float a = Pl[k];
    pw0 += a * Whh[(size_t)k * 768 + j];
    pw1 += a * Whh[(size_t)k * 768 + j + 256];
    pw2 += a * Whh[(size_t)k * 768 + j + 512];
  }
  const float rg = 1.f / (1.f + __expf(-(mw0 + bih[j] + pw0)));
  const float zg = 1.f / (1.f + __expf(-(mw1 + bih[j + 256] + pw1)));
  const float ng = tanhf(mw2 + bih[j + 512] + rg * pw2);
  G2[(size_t)r * 256 + j] = (1.f - zg) * ng + zg * Pv;
}

// ---------------- B480 = t1 @ mapped^T (exact f32) -------------------------
__global__ void sgemm_bt_k(const float* __restrict__ A, const float* __restrict__ W,
                           float* __restrict__ C, int M, int N, int K) {
  const int idx = blockIdx.x * 256 + threadIdx.x;
  if (idx >= M * N) return;
  const int i = idx / N, j = idx % N;
  float s = 0.f;
  const float* a = A + (size_t)i * K;
  const float* w = W + (size_t)j * K;
  for (int k = 0; k < K; ++k) s += a[k] * w[k];
  C[idx] = s;
}

// ---------------- masked softmax for all steps (padded to 512 cols) --------
__global__ void softmax_all_k(const float* __restrict__ part, const float* __restrict__ B480,
                              const int* __restrict__ rel_idx, u16* __restrict__ attn) {
  const int task = blockIdx.x * 4 + (threadIdx.x >> 6);
  const int lane = threadIdx.x & 63;
  const int tt = task >> 13;            // /NT
  const int i  = task & (NT - 1);
  const float* cur = part + (size_t)i * (TT * R) + (size_t)tt * R;
  const float* b = B480 + (size_t)rel_idx[i] * R;
  float v[8];
  float m = -3e38f;
  #pragma unroll
  for (int j = 0; j < 8; ++j) {
    const int r = lane + j * 64;
    float val = -1e9f;
    if (r < R) {
      const float c = cur[r];
      val = (c == 0.f) ? -1e9f : c * b[r];
      m = fmaxf(m, val);
    }
    v[j] = val;
  }
  #pragma unroll
  for (int o = 32; o; o >>= 1) m = fmaxf(m, __shfl_xor(m, o));
  float s = 0.f;
  #pragma unroll
  for (int j = 0; j < 8; ++j) {
    const int r = lane + j * 64;
    if (r < R) { v[j] = __expf(v[j] - m); s += v[j]; }
  }
  #pragma unroll
  for (int o = 32; o; o >>= 1) s += __shfl_xor(s, o);
  const float inv = 1.f / s;
  u16* arow = attn + (size_t)task * RP;
  #pragma unroll
  for (int j = 0; j < 8; ++j) {
    const int r = lane + j * 64;           // covers 0..511 exactly
    arow[r] = (r < R) ? f2b(v[j] * inv) : (u16)0;
  }
}

// ---------------- single-launch 10-step scan -------------------------------
__launch_bounds__(256)
__global__ void scan_k(const u16* __restrict__ WhhT, const float* __restrict__ bhh,
                       const u16* __restrict__ gi_all, float* __restrict__ hbuf) {
  __shared__ __align__(16) u16 As[32 * 256];
  __shared__ __align__(16) u16 Bs[2][192 * 64];
  const int tid = threadIdx.x;
  const int lane = tid & 63;
  const int wv = tid >> 6;
  const int rf = wv >> 1;
  const int ch = wv & 1;
  const int fr = lane & 15;
  const int fq = lane >> 4;
  const int row_l = rf * 16 + fr;
  const int grow = blockIdx.x * 32 + row_l;
  const int sw = (fr & 7) * 8;

  auto stageB = [&](int buf, int cg, int k0) {
    #pragma unroll
    for (int it = 0; it < 6; ++it) {
      const int c = it * 256 + tid;
      const int vr = c >> 3, s = c & 7;
      const int vcol = ((vr >> 6) * 256) + cg * 64 + (vr & 63);
      gload_lds16(WhhT + (size_t)vcol * 256 + k0 + ((s ^ (vr & 7)) * 8),
                  &Bs[buf][(it * 256 + wv * 64) * 8]);
    }
  };

  float hreg[4][2][4];
  #pragma unroll
  for (int cg = 0; cg < 4; ++cg)
    #pragma unroll
    for (int nn = 0; nn < 2; ++nn)
      #pragma unroll
      for (int j = 0; j < 4; ++j) hreg[cg][nn][j] = 0.f;

  for (int t = 0; t < TT; ++t) {
    const u16* gi = gi_all + (size_t)t * NT * 768;
    #pragma unroll
    for (int cg = 0; cg < 4; ++cg) {
      f32x4 acc[6] = {};
      u16x4 gv[3][2];
      #pragma unroll
      for (int nn = 0; nn < 2; ++nn) {
        const int c = cg * 64 + ch * 32 + nn * 16 + fq * 4;
        const size_t gb = (size_t)grow * 768 + c;
        gv[0][nn] = *(const u16x4*)&gi[gb];
        gv[1][nn] = *(const u16x4*)&gi[gb + 256];
        gv[2][nn] = *(const u16x4*)&gi[gb + 512];
      }
      if (t > 0) {
        stageB(0, cg, 0);
        #pragma unroll
        for (int ki = 0; ki < 4; ++ki) {
          const int cb = ki & 1;
          if (ki < 3) {
            stageB(cb ^ 1, cg, (ki + 1) * 64);
            asm volatile("s_waitcnt vmcnt(6)" ::: "memory");
          } else {
            asm volatile("s_waitcnt vmcnt(0)" ::: "memory");
          }
          __builtin_amdgcn_sched_barrier(0);
          __builtin_amdgcn_s_barrier();
          #pragma unroll
          for (int kk = 0; kk < 2; ++kk) {
            const int ko = (ki * 64 + kk * 32 + fq * 8) ^ sw;
            const bf16x8 a = *(const bf16x8*)&As[row_l * 256 + ko];
            const int bo = (kk * 32 + fq * 8) ^ sw;
            #pragma unroll
            for (int g = 0; g < 3; ++g)
              #pragma unroll
              for (int nn = 0; nn < 2; ++nn) {
                const int vr = g * 64 + ch * 32 + nn * 16 + fr;
                const bf16x8 b = *(const bf16x8*)&Bs[cb][vr * 64 + bo];
                acc[g * 2 + nn] =
                    __builtin_amdgcn_mfma_f32_16x16x32_bf16(b, a, acc[g * 2 + nn], 0, 0, 0);
              }
          }
          __builtin_amdgcn_s_barrier();
        }
      }
      #pragma unroll
      for (int nn = 0; nn < 2; ++nn) {
        const int c = cg * 64 + ch * 32 + nn * 16 + fq * 4;
        const f32x4 bn = *(const f32x4*)&bhh[512 + c];
        #pragma unroll
        for (int j = 0; j < 4; ++j) {
          const float rg = 1.f / (1.f + __expf(-(b2f(gv[0][nn][j]) + acc[nn][j])));
          const float zg = 1.f / (1.f + __expf(-(b2f(gv[1][nn][j]) + acc[2 + nn][j])));
          const float ng = tanhf(b2f(gv[2][nn][j]) + rg * (acc[4 + nn][j] + bn[j]));
          hreg[cg][nn][j] = (1.f - zg) * ng + zg * hreg[cg][nn][j];
        }
      }
    }
    #pragma unroll
    for (int cg = 0; cg < 4; ++cg)
      #pragma unroll
      for (int nn = 0; nn < 2; ++nn) {
        const int c = cg * 64 + ch * 32 + nn * 16 + fq * 4;
        u16x4 o;
        #pragma unroll
        for (int j = 0; j < 4; ++j) o[j] = f2b(hreg[cg][nn][j]);
        *(u16x4*)&As[row_l * 256 + (c ^ sw)] = o;
        if (t == TT - 1) {
          f32x4 hv;
          #pragma unroll
          for (int j = 0; j < 4; ++j) hv[j] = hreg[cg][nn][j];
          *(f32x4*)&hbuf[(size_t)grow * 256 + c] = hv;
        }
      }
    __syncthreads();
  }
}

// ---------------- gathers / converts (vectorized) --------------------------
__global__ void gather_sub_k(const float* __restrict__ pre, const int* __restrict__ sub,
                             u16* __restrict__ sb) {
  const int q = blockIdx.x * 256 + threadIdx.x;
  const int i = q >> 6, c = (q & 63) * 4;
  const f32x4 v = *(const f32x4*)&pre[(size_t)sub[i] * H + c];
  u16x4 o;
  #pragma unroll
  for (int j = 0; j < 4; ++j) o[j] = f2b(v[j]);
  *(u16x4*)&sb[(size_t)q * 4] = o;
}
__global__ void cvt_pre_k(const float* __restrict__ pre, u16* __restrict__ pb) {
  const int q = blockIdx.x * 256 + threadIdx.x;
  const f32x4 v = *(const f32x4*)&pre[(size_t)q * 4];
  u16x4 o;
  #pragma unroll
  for (int j = 0; j < 4; ++j) o[j] = f2b(v[j]);
  *(u16x4*)&pb[(size_t)q * 4] = o;
}

// ---------------- pos_i = dot(lhs[i], alignedT[obj[i]]) --------------------
__global__ void pos_k(const u16* __restrict__ lhs, const u16* __restrict__ alT,
                      const int* __restrict__ obj, float* __restrict__ pos) {
  const int row = blockIdx.x * 4 + (threadIdx.x >> 6);
  const int lane = threadIdx.x & 63;
  const u16x4 av = *(const u16x4*)&lhs[(size_t)row * H + lane * 4];
  const u16x4 bv = *(const u16x4*)&alT[(size_t)obj[row] * H + lane * 4];
  float s = 0.f;
  #pragma unroll
  for (int j = 0; j < 4; ++j) s += b2f(av[j]) * b2f(bv[j]);
  #pragma unroll
  for (int o = 32; o; o >>= 1) s += __shfl_down(s, o);
  if (lane == 0) pos[row] = s;
}

// ---------------- final scalar reduction -----------------------------------
__global__ void finalize_k(const float* __restrict__ mp, const float* __restrict__ sp,
                           const float* __restrict__ pos, float* __restrict__ out) {
  const int tid = threadIdx.x;
  float s1 = 0.f, s2 = 0.f, s3 = 0.f;
  for (int i = tid; i < 128; i += 256) s1 += mp[i];
  for (int i = tid; i < 11520; i += 256) s2 += sp[i];
  for (int i = tid; i < 8192; i += 256) s3 += pos[i];
  #pragma unroll
  for (int o = 32; o; o >>= 1) {
    s1 += __shfl_down(s1, o); s2 += __shfl_down(s2, o); s3 += __shfl_down(s3, o);
  }
  __shared__ float r1[4], r2[4], r3[4];
  if ((tid & 63) == 0) { r1[tid >> 6] = s1; r2[tid >> 6] = s2; r3[tid >> 6] = s3; }
  __syncthreads();
  if (tid == 0) {
    const float a = r1[0] + r1[1] + r1[2] + r1[3];
    const float b = r2[0] + r2[1] + r2[2] + r2[3];
    const float c = r3[0] + r3[1] + r3[2] + r3[3];
    out[0] = a / 2097152.f;
    out[1] = (b - c) / 188416000.f;
  }
}

// ---------------- bf16 MFMA GEMM, BK=64, dbuf + counted vmcnt --------------
// MODE 0: C = A@B + bias -> Cf/Cb ; MODE 1: sigmoid/softplus ; MODE 2: lhs+match
template <int MODE>
__launch_bounds__(256)
__global__ void gemm_k(const u16* __restrict__ A, const u16* __restrict__ Bt,
                       const float* __restrict__ bias,
                       float* __restrict__ Cf, u16* __restrict__ Cb,
                       int M, int N, int K,
                       float* __restrict__ out2, float* __restrict__ part,
                       const int* __restrict__ rel_idx, const float* __restrict__ Pf,
                       const float* __restrict__ G2f, const float* __restrict__ hf) {
  __shared__ __align__(16) u16 As[2][128 * 64];
  __shared__ __align__(16) u16 Bs[2][128 * 64];
  __shared__ float red[4];
  const int tid = threadIdx.x;
  const int lane = tid & 63;
  const int wv = tid >> 6;
  const int nbx = gridDim.x;
  int flat = blockIdx.y * nbx + blockIdx.x;
  const int nwg = nbx * gridDim.y;
  if ((nwg & 7) == 0) flat = (flat & 7) * (nwg >> 3) + (flat >> 3);
  const int bx = flat % nbx;
  const int by = flat / nbx;
  const int m0 = by * 128;
  const int n0 = bx * 128;
  const int wm = (wv >> 1) * 64;
  const int wn = (wv & 1) * 64;
  const int fr = lane & 15;
  const int fq = lane >> 4;
  const int sw = (lane & 7) * 8;
  f32x4 acc[4][4] = {};

  auto stage = [&](int buf, int k0) {
    #pragma unroll
    for (int it = 0; it < 4; ++it) {
      const int c = it * 256 + tid;
      const int row = c >> 3, s = c & 7;
      const int sc = (s ^ (row & 7)) * 8;
      int gr = m0 + row; gr = gr < M ? gr : M - 1;
      gload_lds16(A + (size_t)gr * K + k0 + sc, &As[buf][(it * 256 + wv * 64) * 8]);
      int nr = n0 + row; nr = nr < N ? nr : N - 1;
      gload_lds16(Bt + (size_t)nr * K + k0 + sc, &Bs[buf][(it * 256 + wv * 64) * 8]);
    }
  };

  stage(0, 0);
  const int nsteps = K >> 6;
  for (int kt = 0; kt < nsteps; ++kt) {
    const int cb = kt & 1;
    if (kt + 1 < nsteps) {
      stage(cb ^ 1, (kt + 1) * 64);
      asm volatile("s_waitcnt vmcnt(8)" ::: "memory");
    } else {
      asm volatile("s_waitcnt vmcnt(0)" ::: "memory");
    }
    __builtin_amdgcn_sched_barrier(0);
    __builtin_amdgcn_s_barrier();
    #pragma unroll
    for (int kk = 0; kk < 2; ++kk) {
      const int ko = (kk * 32 + fq * 8) ^ sw;
      bf16x8 a[4], b[4];
      #pragma unroll
      for (int mi = 0; mi < 4; ++mi)
        a[mi] = *(const bf16x8*)&As[cb][(wm + mi * 16 + fr) * 64 + ko];
      #pragma unroll
      for (int ni = 0; ni < 4; ++ni)
        b[ni] = *(const bf16x8*)&Bs[cb][(wn + ni * 16 + fr) * 64 + ko];
      #pragma unroll
      for (int mi = 0; mi < 4; ++mi)
        #pragma unroll
        for (int ni = 0; ni < 4; ++ni)
          acc[mi][ni] = __builtin_amdgcn_mfma_f32_16x16x32_bf16(b[ni], a[mi], acc[mi][ni], 0, 0, 0);
    }
    __builtin_amdgcn_s_barrier();
  }

  float local = 0.f;
  #pragma unroll
  for (int mi = 0; mi < 4; ++mi) {
    const int rowm = m0 + wm + mi * 16 + fr;
    int rel = 0;
    if (MODE == 2) rel = rel_idx[rowm];
    #pragma unroll
    for (int ni = 0; ni < 4; ++ni) {
      const int col = n0 + wn + ni * 16 + fq * 4;
      if (rowm < M && col < N) {
        f32x4 v = acc[mi][ni];
        if (MODE == 0) {
          if (bias != nullptr) {
            const f32x4 bv = *(const f32x4*)&bias[col];
            #pragma unroll
            for (int j = 0; j < 4; ++j) v[j] += bv[j];
          }
          if (Cf) *(f32x4*)&Cf[(size_t)rowm * N + col] = v;
          if (Cb) {
            u16x4 o;
            #pragma unroll
            for (int j = 0; j < 4; ++j) o[j] = f2b(v[j]);
            *(u16x4*)&Cb[(size_t)rowm * N + col] = o;
          }
        } else if (MODE == 1) {
          f32x4 sg;
          #pragma unroll
          for (int j = 0; j < 4; ++j) {
            const float s = v[j];
            const float sig = 1.f / (1.f + __expf(-s));
            sg[j] = sig;
            const float om = 1.f - sig;
            local += (om > 0.f) ? -__logf(om) : s;
          }
          *(f32x4*)&out2[(size_t)rowm * N + col] = sg;
        } else {
          const f32x4 bv = *(const f32x4*)&bias[col];
          const f32x4 Pv = *(const f32x4*)&Pf[(size_t)rel * H + col];
          const f32x4 Gv = *(const f32x4*)&G2f[(size_t)rel * H + col];
          const f32x4 hv = *(const f32x4*)&hf[(size_t)rowm * H + col];
          u16x4 o;
          #pragma unroll
          for (int j = 0; j < 4; ++j) {
            const float d = Pv[j] - hv[j];
            local += d * d;
            o[j] = f2b((v[j] + bv[j]) * Gv[j]);
          }
          *(u16x4*)&Cb[(size_t)rowm * N + col] = o;
        }
      }
    }
  }
  if (MODE != 0) {
    #pragma unroll
    for (int o = 32; o; o >>= 1) local += __shfl_down(local, o);
    if (lane == 0) red[wv] = local;
    __syncthreads();
    if (tid == 0) part[blockIdx.y * gridDim.x + blockIdx.x] = red[0] + red[1] + red[2] + red[3];
  }
}

extern "C" void kernel_launch(void* const* d_in, const int* in_sizes, int n_in,
                              void* d_out, int out_size, void* d_ws, size_t ws_size,
                              hipStream_t stream) {
  const float* pre_emb = (const float*)d_in[0];
  const float* r_emb   = (const float*)d_in[1];
  const float* part_e  = (const float*)d_in[2];
  const int*   sub_idx = (const int*)d_in[3];
  const int*   rel_idx = (const int*)d_in[4];
  const int*   obj_idx = (const int*)d_in[5];
  const float* Wm1 = (const float*)d_in[7];  const float* bm1 = (const float*)d_in[8];
  const float* Wm2 = (const float*)d_in[9];  const float* bm2 = (const float*)d_in[10];
  const float* Wattn = (const float*)d_in[11]; const float* battn = (const float*)d_in[12];
  const float* Wh1 = (const float*)d_in[13]; const float* bh1 = (const float*)d_in[14];
  const float* Wh2 = (const float*)d_in[15]; const float* bh2 = (const float*)d_in[16];
  const float* Walign = (const float*)d_in[17]; const float* balign = (const float*)d_in[18];
  const float* Wih = (const float*)d_in[19]; const float* Whh = (const float*)d_in[20];
  const float* bih = (const float*)d_in[21]; const float* bhh = (const float*)d_in[22];
  float* out = (float*)d_out;

  char* w = (char*)d_ws;
  size_t off = 0;
  auto alloc = [&](size_t bytes) -> void* {
    off = (off + 255) & ~(size_t)255;
    void* p = w + off;
    off += bytes;
    return p;
  };
  float* mapped = (float*)alloc((size_t)R * H * 4);
  float* t1     = (float*)alloc((size_t)R * H * 4);
  float* B480   = (float*)alloc((size_t)R * R * 4);
  float* P      = (float*)alloc((size_t)R * H * 4);
  float* G2     = (float*)alloc((size_t)R * H * 4);
  u16* MWT      = (u16*)alloc((size_t)768 * RP * 2);
  u16* WhhT     = (u16*)alloc((size_t)768 * H * 2);
  u16* WalignT  = (u16*)alloc((size_t)H * H * 2);
  float* bsum   = (float*)alloc(768 * 4);
  float* hbuf   = (float*)alloc((size_t)NT * H * 4);
  u16* lhs_b    = (u16*)alloc((size_t)NT * H * 2);
  u16* sub_b    = (u16*)alloc((size_t)NT * H * 2);
  u16* pre_b    = (u16*)alloc((size_t)NE * H * 2);
  u16* alT      = (u16*)alloc((size_t)NE * H * 2);
  float* mpart  = (float*)alloc(128 * 4);
  float* spart  = (float*)alloc(11520 * 4);
  float* posar  = (float*)alloc(8192 * 4);
  u16* attn_all = (u16*)alloc((size_t)TT * NT * RP * 2);
  u16* gi_all   = (u16*)alloc((size_t)TT * NT * 768 * 2);
  if (off > ws_size) return;  // workspace insufficient; fail visibly

  // rank-480 precompute + weight prep (one launch)
  hipMemsetAsync(MWT, 0, (size_t)768 * RP * 2, stream);
  stageA_k<<<480 + 1027, 256, 0, stream>>>(
      r_emb, Wm1, bm1, Wm2, bm2, Wattn, battn, Wih, Wh1, bh1, Wh2, bh2,
      Whh, bhh, bih, Walign, mapped, t1, P, G2, MWT, WhhT, WalignT, bsum);
  sgemm_bt_k<<<(R * R + 255) / 256, 256, 0, stream>>>(t1, mapped, B480, R, R, H);

  // all-step softmax + batched gi GEMM + single-launch scan
  softmax_all_k<<<TT * (NT / 4), 256, 0, stream>>>(part_e, B480, rel_idx, attn_all);
  gemm_k<0><<<dim3(6, TT * (NT / 128)), 256, 0, stream>>>(
      attn_all, MWT, bsum, nullptr, gi_all, TT * NT, 768, RP,
      nullptr, nullptr, nullptr, nullptr, nullptr, nullptr);
  scan_k<<<NT / 32, 256, 0, stream>>>(WhhT, bhh, gi_all, hbuf);

  // sub gather + fused (asub GEMM + lhs + match partials)
  gather_sub_k<<<NT / 4, 256, 0, stream>>>(pre_emb, sub_idx, sub_b);
  gemm_k<2><<<dim3(2, 64), 256, 0, stream>>>(
      sub_b, WalignT, balign, nullptr, lhs_b, NT, H, H,
      nullptr, mpart, rel_idx, P, G2, hbuf);

  // aligned entity table
  cvt_pre_k<<<NE / 4, 256, 0, stream>>>(pre_emb, pre_b);
  gemm_k<0><<<dim3(2, 180), 256, 0, stream>>>(
      pre_b, WalignT, balign, nullptr, alT, NE, H, H,
      nullptr, nullptr, nullptr, nullptr, nullptr, nullptr);

  // final score GEMM with sigmoid + softplus epilogue
  gemm_k<1><<<dim3(180, 64), 256, 0, stream>>>(
      lhs_b, alT, nullptr, nullptr, nullptr, NT, NE, H,
      out + 2, spart, nullptr, nullptr, nullptr, nullptr);

  // pos + final scalars
  pos_k<<<2048, 256, 0, stream>>>(lhs_b, alT, obj_idx, posar);
  finalize_k<<<1, 256, 0, stream>>>(mpart, spart, posar, out);
}

// Round 7
// 1090.247 us; speedup vs baseline: 1.9641x; 1.0031x over previous
//
#include <hip/hip_runtime.h>
#include <hip/hip_bf16.h>
#include <stdint.h>

#define DEV __device__ __forceinline__

typedef unsigned short u16;
typedef __attribute__((ext_vector_type(8))) short bf16x8;
typedef __attribute__((ext_vector_type(4))) float f32x4;
typedef __attribute__((ext_vector_type(4))) unsigned short u16x4;

constexpr int H  = 256;
constexpr int R  = 480;
constexpr int RP = 512;   // padded K for the gi GEMM
constexpr int NE = 23000;
constexpr int NT = 8192;
constexpr int TT = 10;

DEV u16 f2b(float f) {
  union { float f; unsigned u; } x; x.f = f;
  unsigned u = x.u;
  return (u16)((u + 0x7fffu + ((u >> 16) & 1u)) >> 16);
}
DEV float b2f(u16 h) {
  union { unsigned u; float f; } x; x.u = ((unsigned)h) << 16;
  return x.f;
}

DEV void gload_lds16(const u16* g, u16* lds) {
  __builtin_amdgcn_global_load_lds(
      (const __attribute__((address_space(1))) unsigned int*)g,
      (__attribute__((address_space(3))) unsigned int*)lds, 16, 0, 0);
}

// ---------------- fused rank-480 precompute + weight prep ------------------
// Blocks 0..479: row-local chain with f32x4 weight loads (quad outputs/thread,
// k-group split + LDS reduce). Blocks 480..1509: WhhT/WalignT/bsum/MWT-pad.
__launch_bounds__(256)
__global__ void stageA_k(const float* __restrict__ r_emb,
                         const float* __restrict__ Wm1, const float* __restrict__ bm1,
                         const float* __restrict__ Wm2, const float* __restrict__ bm2,
                         const float* __restrict__ Wattn, const float* __restrict__ battn,
                         const float* __restrict__ Wih,
                         const float* __restrict__ Wh1, const float* __restrict__ bh1,
                         const float* __restrict__ Wh2, const float* __restrict__ bh2,
                         const float* __restrict__ Whh, const float* __restrict__ bhh,
                         const float* __restrict__ bih, const float* __restrict__ Walign,
                         float* __restrict__ mapped, float* __restrict__ t1,
                         float* __restrict__ Pg, float* __restrict__ G2,
                         u16* __restrict__ MWT, u16* __restrict__ WhhT,
                         u16* __restrict__ WalignT, float* __restrict__ bsum) {
  const int j = threadIdx.x;
  if (blockIdx.x >= 480) {
    const int b = blockIdx.x - 480;
    if (b < 768) {
      WhhT[(size_t)b * 256 + j] = f2b(Whh[(size_t)j * 768 + b]);
    } else if (b < 1024) {
      const int n = b - 768;
      WalignT[(size_t)n * 256 + j] = f2b(Walign[(size_t)j * 256 + n]);
    } else if (b < 1027) {
      const int c = (b - 1024) * 256 + j;
      if (c < 768) bsum[c] = bih[c] + (c < 512 ? bhh[c] : 0.f);
    } else {
      const int row = (b - 1027) * 256 + j;      // 0..767
      if (row < 768) {
        const u16x4 z = {0, 0, 0, 0};
        #pragma unroll
        for (int c = 480; c < 512; c += 4) *(u16x4*)&MWT[(size_t)row * RP + c] = z;
      }
    }
    return;
  }
  __shared__ float re[256], hid[512], mp[256], p1l[256], Pl[256];
  __shared__ float mwl[768], pwl[768];
  __shared__ f32x4 red4[256];
  const int r = blockIdx.x;
  const f32x4 z4 = {0.f, 0.f, 0.f, 0.f};
  re[j] = r_emb[(size_t)r * 256 + j];
  __syncthreads();
  // hidden = re @ Wm1 + bm1 : N=512, K=256 (Q=128, G=2)
  {
    const int q = j & 127, g = j >> 7;
    f32x4 acc = (g == 0) ? *(const f32x4*)&bm1[q * 4] : z4;
    for (int k = g * 128; k < g * 128 + 128; ++k)
      acc += re[k] * *(const f32x4*)&Wm1[(size_t)k * 512 + q * 4];
    red4[j] = acc;
    __syncthreads();
    if (j < 128) *(f32x4*)&hid[j * 4] = red4[j] + red4[j + 128];
    __syncthreads();
  }
  // mapped = hid @ Wm2 + bm2 : N=256, K=512 (Q=64, G=4)
  {
    const int q = j & 63, g = j >> 6;
    f32x4 acc = (g == 0) ? *(const f32x4*)&bm2[q * 4] : z4;
    for (int k = g * 128; k < g * 128 + 128; ++k)
      acc += hid[k] * *(const f32x4*)&Wm2[(size_t)k * 256 + q * 4];
    red4[j] = acc;
    __syncthreads();
    if (j < 64) {
      const f32x4 s = red4[j] + red4[j + 64] + red4[j + 128] + red4[j + 192];
      *(f32x4*)&mp[j * 4] = s;
      *(f32x4*)&mapped[(size_t)r * 256 + j * 4] = s;
    }
    __syncthreads();
  }
  // t1 = mp @ Wattn + battn : N=256, K=256 (Q=64, G=4)
  {
    const int q = j & 63, g = j >> 6;
    f32x4 acc = (g == 0) ? *(const f32x4*)&battn[q * 4] : z4;
    for (int k = g * 64; k < g * 64 + 64; ++k)
      acc += mp[k] * *(const f32x4*)&Wattn[(size_t)k * 256 + q * 4];
    red4[j] = acc;
    __syncthreads();
    if (j < 64)
      *(f32x4*)&t1[(size_t)r * 256 + j * 4] =
          red4[j] + red4[j + 64] + red4[j + 128] + red4[j + 192];
    __syncthreads();
  }
  // MW = mp @ Wih : N=768, K=256 (Q=192, G=1) -> mwl + MWT (bf16 transposed)
  if (j < 192) {
    f32x4 acc = z4;
    for (int k = 0; k < 256; ++k)
      acc += mp[k] * *(const f32x4*)&Wih[(size_t)k * 768 + j * 4];
    *(f32x4*)&mwl[j * 4] = acc;
    #pragma unroll
    for (int c = 0; c < 4; ++c) MWT[(size_t)(j * 4 + c) * RP + r] = f2b(acc[c]);
  }
  __syncthreads();
  // p1 = mp @ Wh1 + bh1 : N=256 (Q=64, G=4)
  {
    const int q = j & 63, g = j >> 6;
    f32x4 acc = (g == 0) ? *(const f32x4*)&bh1[q * 4] : z4;
    for (int k = g * 64; k < g * 64 + 64; ++k)
      acc += mp[k] * *(const f32x4*)&Wh1[(size_t)k * 256 + q * 4];
    red4[j] = acc;
    __syncthreads();
    if (j < 64) *(f32x4*)&p1l[j * 4] = red4[j] + red4[j + 64] + red4[j + 128] + red4[j + 192];
    __syncthreads();
  }
  // P = 0.1*(p1 @ Wh2 + bh2) + mp : N=256 (Q=64, G=4)
  {
    const int q = j & 63, g = j >> 6;
    f32x4 acc = (g == 0) ? *(const f32x4*)&bh2[q * 4] : z4;
    for (int k = g * 64; k < g * 64 + 64; ++k)
      acc += p1l[k] * *(const f32x4*)&Wh2[(size_t)k * 256 + q * 4];
    red4[j] = acc;
    __syncthreads();
    if (j < 64) {
      f32x4 s = red4[j] + red4[j + 64] + red4[j + 128] + red4[j + 192];
      const f32x4 mv = *(const f32x4*)&mp[j * 4];
      #pragma unroll
      for (int c = 0; c < 4; ++c) s[c] = 0.1f * s[c] + mv[c];
      *(f32x4*)&Pl[j * 4] = s;
      *(f32x4*)&Pg[(size_t)r * 256 + j * 4] = s;
    }
    __syncthreads();
  }
  // PW = P @ Whh + bhh : N=768 (Q=192, G=1) -> pwl
  if (j < 192) {
    f32x4 acc = *(const f32x4*)&bhh[j * 4];
    for (int k = 0; k < 256; ++k)
      acc += Pl[k] * *(const f32x4*)&Whh[(size_t)k * 768 + j * 4];
    *(f32x4*)&pwl[j * 4] = acc;
  }
  __syncthreads();
  // G2 = gru(x=mp-derived MW, h=P)
  {
    const float rg = 1.f / (1.f + __expf(-(mwl[j] + bih[j] + pwl[j])));
    const float zg = 1.f / (1.f + __expf(-(mwl[j + 256] + bih[j + 256] + pwl[j + 256])));
    const float ng = tanhf(mwl[j + 512] + bih[j + 512] + rg * pwl[j + 512]);
    G2[(size_t)r * 256 + j] = (1.f - zg) * ng + zg * Pl[j];
  }
}

// ---------------- B480 = t1 @ mapped^T (exact f32, f32x4 dot) --------------
__global__ void sgemm_bt_k(const float* __restrict__ A, const float* __restrict__ W,
                           float* __restrict__ C, int M, int N, int K) {
  const int idx = blockIdx.x * 256 + threadIdx.x;
  if (idx >= M * N) return;
  const int i = idx / N, j = idx % N;
  const f32x4* a4 = (const f32x4*)(A + (size_t)i * K);
  const f32x4* w4 = (const f32x4*)(W + (size_t)j * K);
  f32x4 acc = {0.f, 0.f, 0.f, 0.f};
  for (int k = 0; k < K / 4; ++k) acc += a4[k] * w4[k];
  C[idx] = acc[0] + acc[1] + acc[2] + acc[3];
}

// ---------------- masked softmax for all steps (f32x4 loads) ---------------
__global__ void softmax_all_k(const float* __restrict__ part, const float* __restrict__ B480,
                              const int* __restrict__ rel_idx, u16* __restrict__ attn) {
  const int task = blockIdx.x * 4 + (threadIdx.x >> 6);
  const int lane = threadIdx.x & 63;
  const int tt = task >> 13;            // /NT
  const int i  = task & (NT - 1);
  const float* cur = part + (size_t)i * (TT * R) + (size_t)tt * R;
  const float* b = B480 + (size_t)rel_idx[i] * R;
  f32x4 v[2];
  float m = -3e38f;
  const bool act1 = lane < 56;          // jj=1 covers r 256..479 for lanes 0..55
  #pragma unroll
  for (int jj = 0; jj < 2; ++jj) {
    const int r0 = jj * 256 + lane * 4;
    f32x4 val = {-1e9f, -1e9f, -1e9f, -1e9f};
    if (jj == 0 || act1) {
      const f32x4 c4 = *(const f32x4*)&cur[r0];
      const f32x4 b4 = *(const f32x4*)&b[r0];
      #pragma unroll
      for (int x = 0; x < 4; ++x) {
        val[x] = (c4[x] == 0.f) ? -1e9f : c4[x] * b4[x];
        m = fmaxf(m, val[x]);
      }
    }
    v[jj] = val;
  }
  #pragma unroll
  for (int o = 32; o; o >>= 1) m = fmaxf(m, __shfl_xor(m, o));
  float s = 0.f;
  #pragma unroll
  for (int jj = 0; jj < 2; ++jj) {
    if (jj == 0 || act1) {
      #pragma unroll
      for (int x = 0; x < 4; ++x) { v[jj][x] = __expf(v[jj][x] - m); s += v[jj][x]; }
    }
  }
  #pragma unroll
  for (int o = 32; o; o >>= 1) s += __shfl_xor(s, o);
  const float inv = 1.f / s;
  u16* arow = attn + (size_t)task * RP;
  #pragma unroll
  for (int jj = 0; jj < 2; ++jj) {
    const int r0 = jj * 256 + lane * 4;
    u16x4 o = {0, 0, 0, 0};
    if (jj == 0 || act1) {
      #pragma unroll
      for (int x = 0; x < 4; ++x) o[x] = f2b(v[jj][x] * inv);
    }
    *(u16x4*)&arow[r0] = o;
  }
}

// ---------------- single-launch 10-step scan -------------------------------
__launch_bounds__(256)
__global__ void scan_k(const u16* __restrict__ WhhT, const float* __restrict__ bhh,
                       const u16* __restrict__ gi_all, float* __restrict__ hbuf) {
  __shared__ __align__(16) u16 As[32 * 256];
  __shared__ __align__(16) u16 Bs[2][192 * 64];
  const int tid = threadIdx.x;
  const int lane = tid & 63;
  const int wv = tid >> 6;
  const int rf = wv >> 1;
  const int ch = wv & 1;
  const int fr = lane & 15;
  const int fq = lane >> 4;
  const int row_l = rf * 16 + fr;
  const int grow = blockIdx.x * 32 + row_l;
  const int sw = (fr & 7) * 8;

  auto stageB = [&](int buf, int cg, int k0) {
    #pragma unroll
    for (int it = 0; it < 6; ++it) {
      const int c = it * 256 + tid;
      const int vr = c >> 3, s = c & 7;
      const int vcol = ((vr >> 6) * 256) + cg * 64 + (vr & 63);
      gload_lds16(WhhT + (size_t)vcol * 256 + k0 + ((s ^ (vr & 7)) * 8),
                  &Bs[buf][(it * 256 + wv * 64) * 8]);
    }
  };

  float hreg[4][2][4];
  #pragma unroll
  for (int cg = 0; cg < 4; ++cg)
    #pragma unroll
    for (int nn = 0; nn < 2; ++nn)
      #pragma unroll
      for (int j = 0; j < 4; ++j) hreg[cg][nn][j] = 0.f;

  for (int t = 0; t < TT; ++t) {
    const u16* gi = gi_all + (size_t)t * NT * 768;
    #pragma unroll
    for (int cg = 0; cg < 4; ++cg) {
      f32x4 acc[6] = {};
      u16x4 gv[3][2];
      #pragma unroll
      for (int nn = 0; nn < 2; ++nn) {
        const int c = cg * 64 + ch * 32 + nn * 16 + fq * 4;
        const size_t gb = (size_t)grow * 768 + c;
        gv[0][nn] = *(const u16x4*)&gi[gb];
        gv[1][nn] = *(const u16x4*)&gi[gb + 256];
        gv[2][nn] = *(const u16x4*)&gi[gb + 512];
      }
      if (t > 0) {
        stageB(0, cg, 0);
        #pragma unroll
        for (int ki = 0; ki < 4; ++ki) {
          const int cb = ki & 1;
          if (ki < 3) {
            stageB(cb ^ 1, cg, (ki + 1) * 64);
            asm volatile("s_waitcnt vmcnt(6)" ::: "memory");
          } else {
            asm volatile("s_waitcnt vmcnt(0)" ::: "memory");
          }
          __builtin_amdgcn_sched_barrier(0);
          __builtin_amdgcn_s_barrier();
          #pragma unroll
          for (int kk = 0; kk < 2; ++kk) {
            const int ko = (ki * 64 + kk * 32 + fq * 8) ^ sw;
            const bf16x8 a = *(const bf16x8*)&As[row_l * 256 + ko];
            const int bo = (kk * 32 + fq * 8) ^ sw;
            #pragma unroll
            for (int g = 0; g < 3; ++g)
              #pragma unroll
              for (int nn = 0; nn < 2; ++nn) {
                const int vr = g * 64 + ch * 32 + nn * 16 + fr;
                const bf16x8 b = *(const bf16x8*)&Bs[cb][vr * 64 + bo];
                acc[g * 2 + nn] =
                    __builtin_amdgcn_mfma_f32_16x16x32_bf16(b, a, acc[g * 2 + nn], 0, 0, 0);
              }
          }
          __builtin_amdgcn_s_barrier();
        }
      }
      #pragma unroll
      for (int nn = 0; nn < 2; ++nn) {
        const int c = cg * 64 + ch * 32 + nn * 16 + fq * 4;
        const f32x4 bn = *(const f32x4*)&bhh[512 + c];
        #pragma unroll
        for (int j = 0; j < 4; ++j) {
          const float rg = 1.f / (1.f + __expf(-(b2f(gv[0][nn][j]) + acc[nn][j])));
          const float zg = 1.f / (1.f + __expf(-(b2f(gv[1][nn][j]) + acc[2 + nn][j])));
          const float ng = tanhf(b2f(gv[2][nn][j]) + rg * (acc[4 + nn][j] + bn[j]));
          hreg[cg][nn][j] = (1.f - zg) * ng + zg * hreg[cg][nn][j];
        }
      }
    }
    #pragma unroll
    for (int cg = 0; cg < 4; ++cg)
      #pragma unroll
      for (int nn = 0; nn < 2; ++nn) {
        const int c = cg * 64 + ch * 32 + nn * 16 + fq * 4;
        u16x4 o;
        #pragma unroll
        for (int j = 0; j < 4; ++j) o[j] = f2b(hreg[cg][nn][j]);
        *(u16x4*)&As[row_l * 256 + (c ^ sw)] = o;
        if (t == TT - 1) {
          f32x4 hv;
          #pragma unroll
          for (int j = 0; j < 4; ++j) hv[j] = hreg[cg][nn][j];
          *(f32x4*)&hbuf[(size_t)grow * 256 + c] = hv;
        }
      }
    __syncthreads();
  }
}

// ---------------- gathers / converts (vectorized) --------------------------
__global__ void gather_sub_k(const float* __restrict__ pre, const int* __restrict__ sub,
                             u16* __restrict__ sb) {
  const int q = blockIdx.x * 256 + threadIdx.x;
  const int i = q >> 6, c = (q & 63) * 4;
  const f32x4 v = *(const f32x4*)&pre[(size_t)sub[i] * H + c];
  u16x4 o;
  #pragma unroll
  for (int j = 0; j < 4; ++j) o[j] = f2b(v[j]);
  *(u16x4*)&sb[(size_t)q * 4] = o;
}
__global__ void cvt_pre_k(const float* __restrict__ pre, u16* __restrict__ pb) {
  const int q = blockIdx.x * 256 + threadIdx.x;
  const f32x4 v = *(const f32x4*)&pre[(size_t)q * 4];
  u16x4 o;
  #pragma unroll
  for (int j = 0; j < 4; ++j) o[j] = f2b(v[j]);
  *(u16x4*)&pb[(size_t)q * 4] = o;
}

// ---------------- final scalar reduction -----------------------------------
__global__ void finalize_k(const float* __restrict__ mp, const float* __restrict__ sp,
                           float* __restrict__ out) {
  const int tid = threadIdx.x;
  float s1 = 0.f, s2 = 0.f;
  for (int i = tid; i < 128; i += 256) s1 += mp[i];
  for (int i = tid; i < 11520; i += 256) s2 += sp[i];
  #pragma unroll
  for (int o = 32; o; o >>= 1) {
    s1 += __shfl_down(s1, o); s2 += __shfl_down(s2, o);
  }
  __shared__ float r1[4], r2[4];
  if ((tid & 63) == 0) { r1[tid >> 6] = s1; r2[tid >> 6] = s2; }
  __syncthreads();
  if (tid == 0) {
    const float a = r1[0] + r1[1] + r1[2] + r1[3];
    const float b = r2[0] + r2[1] + r2[2] + r2[3];
    out[0] = a / 2097152.f;               // mean over 8192*256
    out[1] = b / 188416000.f;             // (softplus - pos) already combined
  }
}

// ---------------- bf16 MFMA GEMM, BK=64, dbuf + counted vmcnt --------------
// MODE 0: C = A@B + bias -> Cf/Cb
// MODE 1: sigmoid -> out2, (softplus - pos) partials -> part (idx = obj rows)
// MODE 2: asub epilogue: lhs = (v+balign)*G2[rel], match partials -> part
template <int MODE>
__launch_bounds__(256)
__global__ void gemm_k(const u16* __restrict__ A, const u16* __restrict__ Bt,
                       const float* __restrict__ bias,
                       float* __restrict__ Cf, u16* __restrict__ Cb,
                       int M, int N, int K,
                       float* __restrict__ out2, float* __restrict__ part,
                       const int* __restrict__ idxv, const float* __restrict__ Pf,
                       const float* __restrict__ G2f, const float* __restrict__ hf) {
  __shared__ __align__(16) u16 As[2][128 * 64];
  __shared__ __align__(16) u16 Bs[2][128 * 64];
  __shared__ float red[4];
  const int tid = threadIdx.x;
  const int lane = tid & 63;
  const int wv = tid >> 6;
  const int nbx = gridDim.x;
  int flat = blockIdx.y * nbx + blockIdx.x;
  const int nwg = nbx * gridDim.y;
  if ((nwg & 7) == 0) flat = (flat & 7) * (nwg >> 3) + (flat >> 3);
  const int bx = flat % nbx;
  const int by = flat / nbx;
  const int m0 = by * 128;
  const int n0 = bx * 128;
  const int wm = (wv >> 1) * 64;
  const int wn = (wv & 1) * 64;
  const int fr = lane & 15;
  const int fq = lane >> 4;
  const int sw = (lane & 7) * 8;
  f32x4 acc[4][4] = {};

  auto stage = [&](int buf, int k0) {
    #pragma unroll
    for (int it = 0; it < 4; ++it) {
      const int c = it * 256 + tid;
      const int row = c >> 3, s = c & 7;
      const int sc = (s ^ (row & 7)) * 8;
      int gr = m0 + row; gr = gr < M ? gr : M - 1;
      gload_lds16(A + (size_t)gr * K + k0 + sc, &As[buf][(it * 256 + wv * 64) * 8]);
      int nr = n0 + row; nr = nr < N ? nr : N - 1;
      gload_lds16(Bt + (size_t)nr * K + k0 + sc, &Bs[buf][(it * 256 + wv * 64) * 8]);
    }
  };

  stage(0, 0);
  const int nsteps = K >> 6;
  for (int kt = 0; kt < nsteps; ++kt) {
    const int cb = kt & 1;
    if (kt + 1 < nsteps) {
      stage(cb ^ 1, (kt + 1) * 64);
      asm volatile("s_waitcnt vmcnt(8)" ::: "memory");
    } else {
      asm volatile("s_waitcnt vmcnt(0)" ::: "memory");
    }
    __builtin_amdgcn_sched_barrier(0);
    __builtin_amdgcn_s_barrier();
    #pragma unroll
    for (int kk = 0; kk < 2; ++kk) {
      const int ko = (kk * 32 + fq * 8) ^ sw;
      bf16x8 a[4], b[4];
      #pragma unroll
      for (int mi = 0; mi < 4; ++mi)
        a[mi] = *(const bf16x8*)&As[cb][(wm + mi * 16 + fr) * 64 + ko];
      #pragma unroll
      for (int ni = 0; ni < 4; ++ni)
        b[ni] = *(const bf16x8*)&Bs[cb][(wn + ni * 16 + fr) * 64 + ko];
      #pragma unroll
      for (int mi = 0; mi < 4; ++mi)
        #pragma unroll
        for (int ni = 0; ni < 4; ++ni)
          acc[mi][ni] = __builtin_amdgcn_mfma_f32_16x16x32_bf16(b[ni], a[mi], acc[mi][ni], 0, 0, 0);
    }
    __builtin_amdgcn_s_barrier();
  }

  float local = 0.f;
  #pragma unroll
  for (int mi = 0; mi < 4; ++mi) {
    const int rowm = m0 + wm + mi * 16 + fr;
    int iv = 0;
    if (MODE != 0) iv = idxv[rowm < M ? rowm : M - 1];   // MODE1: obj, MODE2: rel
    #pragma unroll
    for (int ni = 0; ni < 4; ++ni) {
      const int col = n0 + wn + ni * 16 + fq * 4;
      if (rowm < M && col < N) {
        f32x4 v = acc[mi][ni];
        if (MODE == 0) {
          if (bias != nullptr) {
            const f32x4 bv = *(const f32x4*)&bias[col];
            #pragma unroll
            for (int j = 0; j < 4; ++j) v[j] += bv[j];
          }
          if (Cf) *(f32x4*)&Cf[(size_t)rowm * N + col] = v;
          if (Cb) {
            u16x4 o;
            #pragma unroll
            for (int j = 0; j < 4; ++j) o[j] = f2b(v[j]);
            *(u16x4*)&Cb[(size_t)rowm * N + col] = o;
          }
        } else if (MODE == 1) {
          f32x4 sg;
          #pragma unroll
          for (int j = 0; j < 4; ++j) {
            const float s = v[j];
            const float sig = 1.f / (1.f + __expf(-s));
            sg[j] = sig;
            const float om = 1.f - sig;
            local += (om > 0.f) ? -__logf(om) : s;     // softplus(s)
            if (col + j == iv) local -= s;             // pos fold
          }
          *(f32x4*)&out2[(size_t)rowm * N + col] = sg;
        } else {
          const f32x4 bv = *(const f32x4*)&bias[col];
          const f32x4 Pv = *(const f32x4*)&Pf[(size_t)iv * H + col];
          const f32x4 Gv = *(const f32x4*)&G2f[(size_t)iv * H + col];
          const f32x4 hv = *(const f32x4*)&hf[(size_t)rowm * H + col];
          u16x4 o;
          #pragma unroll
          for (int j = 0; j < 4; ++j) {
            const float d = Pv[j] - hv[j];
            local += d * d;
            o[j] = f2b((v[j] + bv[j]) * Gv[j]);
          }
          *(u16x4*)&Cb[(size_t)rowm * N + col] = o;
        }
      }
    }
  }
  if (MODE != 0) {
    #pragma unroll
    for (int o = 32; o; o >>= 1) local += __shfl_down(local, o);
    if (lane == 0) red[wv] = local;
    __syncthreads();
    if (tid == 0) part[blockIdx.y * gridDim.x + blockIdx.x] = red[0] + red[1] + red[2] + red[3];
  }
}

extern "C" void kernel_launch(void* const* d_in, const int* in_sizes, int n_in,
                              void* d_out, int out_size, void* d_ws, size_t ws_size,
                              hipStream_t stream) {
  const float* pre_emb = (const float*)d_in[0];
  const float* r_emb   = (const float*)d_in[1];
  const float* part_e  = (const float*)d_in[2];
  const int*   sub_idx = (const int*)d_in[3];
  const int*   rel_idx = (const int*)d_in[4];
  const int*   obj_idx = (const int*)d_in[5];
  const float* Wm1 = (const float*)d_in[7];  const float* bm1 = (const float*)d_in[8];
  const float* Wm2 = (const float*)d_in[9];  const float* bm2 = (const float*)d_in[10];
  const float* Wattn = (const float*)d_in[11]; const float* battn = (const float*)d_in[12];
  const float* Wh1 = (const float*)d_in[13]; const float* bh1 = (const float*)d_in[14];
  const float* Wh2 = (const float*)d_in[15]; const float* bh2 = (const float*)d_in[16];
  const float* Walign = (const float*)d_in[17]; const float* balign = (const float*)d_in[18];
  const float* Wih = (const float*)d_in[19]; const float* Whh = (const float*)d_in[20];
  const float* bih = (const float*)d_in[21]; const float* bhh = (const float*)d_in[22];
  float* out = (float*)d_out;

  char* w = (char*)d_ws;
  size_t off = 0;
  auto alloc = [&](size_t bytes) -> void* {
    off = (off + 255) & ~(size_t)255;
    void* p = w + off;
    off += bytes;
    return p;
  };
  float* mapped = (float*)alloc((size_t)R * H * 4);
  float* t1     = (float*)alloc((size_t)R * H * 4);
  float* B480   = (float*)alloc((size_t)R * R * 4);
  float* P      = (float*)alloc((size_t)R * H * 4);
  float* G2     = (float*)alloc((size_t)R * H * 4);
  u16* MWT      = (u16*)alloc((size_t)768 * RP * 2);
  u16* WhhT     = (u16*)alloc((size_t)768 * H * 2);
  u16* WalignT  = (u16*)alloc((size_t)H * H * 2);
  float* bsum   = (float*)alloc(768 * 4);
  float* hbuf   = (float*)alloc((size_t)NT * H * 4);
  u16* lhs_b    = (u16*)alloc((size_t)NT * H * 2);
  u16* sub_b    = (u16*)alloc((size_t)NT * H * 2);
  u16* pre_b    = (u16*)alloc((size_t)NE * H * 2);
  u16* alT      = (u16*)alloc((size_t)NE * H * 2);
  float* mpart  = (float*)alloc(128 * 4);
  float* spart  = (float*)alloc(11520 * 4);
  u16* attn_all = (u16*)alloc((size_t)TT * NT * RP * 2);
  u16* gi_all   = (u16*)alloc((size_t)TT * NT * 768 * 2);
  if (off > ws_size) return;  // workspace insufficient; fail visibly

  // rank-480 precompute + weight prep + MWT pad (one launch)
  stageA_k<<<480 + 1030, 256, 0, stream>>>(
      r_emb, Wm1, bm1, Wm2, bm2, Wattn, battn, Wih, Wh1, bh1, Wh2, bh2,
      Whh, bhh, bih, Walign, mapped, t1, P, G2, MWT, WhhT, WalignT, bsum);
  sgemm_bt_k<<<(R * R + 255) / 256, 256, 0, stream>>>(t1, mapped, B480, R, R, H);

  // all-step softmax + batched gi GEMM + single-launch scan
  softmax_all_k<<<TT * (NT / 4), 256, 0, stream>>>(part_e, B480, rel_idx, attn_all);
  gemm_k<0><<<dim3(6, TT * (NT / 128)), 256, 0, stream>>>(
      attn_all, MWT, bsum, nullptr, gi_all, TT * NT, 768, RP,
      nullptr, nullptr, nullptr, nullptr, nullptr, nullptr);
  scan_k<<<NT / 32, 256, 0, stream>>>(WhhT, bhh, gi_all, hbuf);

  // sub gather + fused (asub GEMM + lhs + match partials)
  gather_sub_k<<<NT / 4, 256, 0, stream>>>(pre_emb, sub_idx, sub_b);
  gemm_k<2><<<dim3(2, 64), 256, 0, stream>>>(
      sub_b, WalignT, balign, nullptr, lhs_b, NT, H, H,
      nullptr, mpart, rel_idx, P, G2, hbuf);

  // aligned entity table
  cvt_pre_k<<<NE / 4, 256, 0, stream>>>(pre_emb, pre_b);
  gemm_k<0><<<dim3(2, 180), 256, 0, stream>>>(
      pre_b, WalignT, balign, nullptr, alT, NE, H, H,
      nullptr, nullptr, nullptr, nullptr, nullptr, nullptr);

  // final score GEMM: sigmoid + (softplus - pos) partials
  gemm_k<1><<<dim3(180, 64), 256, 0, stream>>>(
      lhs_b, alT, nullptr, nullptr, nullptr, NT, NE, H,
      out + 2, spart, obj_idx, nullptr, nullptr, nullptr);

  // final scalars
  finalize_k<<<1, 256, 0, stream>>>(mpart, spart, out);
}